// Round 13
// baseline (3773.902 us; speedup 1.0000x reference)
//
#include <hip/hip_runtime.h>
#include <cstdint>
#include <cstddef>

// ---------------------------------------------------------------------------
//   x:[4096,1,30,30] -> conv1(32,3x3)+relu -> conv2(64,3x3)+relu -> maxpool2
//   -> flatten [4096,10816] -> MoE(top2, 8 experts, 10816->128) -> relu
//   -> MoE(top2, 8 experts, 128->10) -> log_softmax
//   outputs: logp[4096,10], gt_l1[4096,8], gt_l2[4096,8], loss[1]
// ---------------------------------------------------------------------------

// ws layout (bytes)
static const size_t OFF_HFLAT = 0;                                        // 177,209,344
static const size_t OFF_H2Q   = (size_t)4096 * 10816 * 4;                 // 4096*4*128*4 = 8,388,608
static const size_t OFF_ROWS  = OFF_H2Q + (size_t)4096 * 4 * 128 * 4;     // 8*4096*4
static const size_t OFF_GATES = OFF_ROWS + (size_t)8 * 4096 * 4;          // 8*4096*4
static const size_t OFF_SMALL = OFF_GATES + (size_t)8 * 4096 * 4;         // 40*4
// small: [0..7] cnt(int) | [8..15] imp1 | [16..23] load1 | [24..31] imp2 | [32..39] load2

// ---------------- fused conv1 -> conv2 -> maxpool ---------------------------
// One 832-thread block per image (grid 4096), all 64 oc, SINGLE PASS.
// ROUND 12 bug: 512 threads x 4oc x 1row can only cover 32 oc x 16 rows
// (ocg=tid&7 dropped oc 32..63 -> half of s_out was garbage). Exact coverage
// of 64oc x 13 pooled rows at 4oc/thread x 1row needs 16 ocg x 13 pr x 4 ct
// = 832 threads (13 waves).
// Thread map: ct = tid/208 (contiguous 208-thread quarters: only wave 9
// straddles the TCp=3/4 boundary -> 1 of 13 waves diverges), pr =
// (tid%208)>>4 in 0..12 exact (no masked rows), ocg = tid&15 (oc ocg*4..+3).
// vs round 7's two-band: conv2 issue 832 vs 1024 thread-streams (-19%),
// conv1 staging 28 vs 36 rows, barriers 10 vs 17, and 13 waves/CU resident
// vs 8 (the 1-block/CU limit is LDS-driven, independent of block size).
// LAUNCH-BOUNDS LAW (rounds 0-8): declared min-waves/EU w -> VGPR ~ 256/w;
// (832,2) -> 128 VGPR, zero spill (r7-proven live set), and 4-wave SIMD
// packing (4x128=512) keeps the 13-wave block launchable.
// Inner loop = round 7's exact proven conv2_accum (4 row buffers, unroll 2).
// Epilogue: full pooled image staged in s_out, single dense aligned copy-out
// (13*832 = 10816 exact).

template<int PC>
__device__ __forceinline__ void ld_row(float* r, const float* __restrict__ p)
{
    #pragma unroll
    for (int c = 0; c < PC; c += 2) {
        float2 t = *(const float2*)(p + c);
        r[c] = t.x; r[c + 1] = t.y;
    }
}

template<int TC>
__device__ __forceinline__ void fma_ky(float acc[4][2][8], const float* ra, const float* rb,
                                       const float* __restrict__ wk)
{
    #pragma unroll
    for (int kx = 0; kx < 3; ++kx) {
        float4 w = *(const float4*)(wk + kx * 64);   // [kk][oc(64)]
        #pragma unroll
        for (int c = 0; c < 2 * TC; ++c) {
            float ia = ra[c + kx], ib = rb[c + kx];
            acc[0][0][c] = fmaf(ia, w.x, acc[0][0][c]);
            acc[1][0][c] = fmaf(ia, w.y, acc[1][0][c]);
            acc[2][0][c] = fmaf(ia, w.z, acc[2][0][c]);
            acc[3][0][c] = fmaf(ia, w.w, acc[3][0][c]);
            acc[0][1][c] = fmaf(ib, w.x, acc[0][1][c]);
            acc[1][1][c] = fmaf(ib, w.y, acc[1][1][c]);
            acc[2][1][c] = fmaf(ib, w.z, acc[2][1][c]);
            acc[3][1][c] = fmaf(ib, w.w, acc[3][1][c]);
        }
    }
}

template<int TC>
__device__ __forceinline__ void conv2_accum(const float* __restrict__ hb,
                                            const float* __restrict__ wb,
                                            float acc[4][2][8])
{
    #pragma unroll 2
    for (int icl = 0; icl < 8; ++icl) {
        const float* h = hb + icl * 784;   // [icl][r(28)][c(28)]
        const float* w = wb + icl * 576;   // [icl][kk 0..8][64]
        float r0[2 * TC + 2], r1[2 * TC + 2], r2[2 * TC + 2], r3[2 * TC + 2];
        ld_row<2 * TC + 2>(r0, h);
        ld_row<2 * TC + 2>(r1, h + 28);
        fma_ky<TC>(acc, r0, r1, w);
        ld_row<2 * TC + 2>(r2, h + 56);
        fma_ky<TC>(acc, r1, r2, w + 192);
        ld_row<2 * TC + 2>(r3, h + 84);
        fma_ky<TC>(acc, r2, r3, w + 384);
    }
}

__global__ __launch_bounds__(832, 2)
void conv_fused(const float* __restrict__ x,
                const float* __restrict__ w1, const float* __restrict__ b1,
                const float* __restrict__ w2, const float* __restrict__ b2,
                float* __restrict__ hflat)
{
    __shared__ float s_in[900];      // full image [30][30], staged once
    __shared__ float s_w1[288];
    __shared__ float s_h1[6272];     // [icl(8)][r(28)][c(28)] chunk of conv1 out
    __shared__ float s_w2c[4608];    // [kk(72)=icl*9+k][oc(64)] current ic-chunk
    __shared__ float s_out[10816];   // full pooled image [64 oc][13][13]
    // total: 900+288+6272+4608+10816 = 22,884 floats = 91,536 B (1 block/CU)

    const int img = blockIdx.x, tid = threadIdx.x;

    const float* xin = x + (size_t)img * 900;
    for (int i = tid; i < 900; i += 832) s_in[i] = xin[i];
    if (tid < 288) s_w1[tid] = w1[tid];
    __syncthreads();   // orders preamble staging with all later readers

    const int ct  = tid / 208;            // 0..3 col quarter (208-thread chunks)
    const int rem = tid - ct * 208;
    const int pr  = rem >> 4;             // 0..12 pooled row (exact, no mask)
    const int ocg = tid & 15;             // 0..15 -> oc ocg*4..+3 (208%16==0)
    const int c0  = ct * 6;               // pre-col start: 0,6,12,18
    const int pc0 = ct * 3;               // pooled-col start
    const int TCp = (ct < 3) ? 3 : 4;     // pooled cols this thread

    const float* hb = s_h1 + 2 * pr * 28 + c0;   // pre-rows 2pr..2pr+3
    const float* wb = s_w2c + ocg * 4;

    float acc[4][2][8];
    #pragma unroll
    for (int o = 0; o < 4; ++o) {
        float bb = b2[ocg * 4 + o];              // L2-hot global (256 B total)
        #pragma unroll
        for (int r = 0; r < 2; ++r)
            #pragma unroll
            for (int c = 0; c < 8; ++c) acc[o][r][c] = bb;
    }

    #pragma unroll 1
    for (int ch = 0; ch < 4; ++ch) {             // 4 chunks x 8 ic
        __syncthreads();   // previous compute done before restaging s_h1/s_w2c
        // --- stage conv1: rows 0..27, cols 0..27, ic chunk ch*8..+7 ---
        #pragma unroll
        for (int it = 0; it < 8; ++it) {
            int i2 = it * 832 + tid;             // 0..6271 used (8*28*28)
            if (i2 < 6272) {
                int q = i2 / 28;                 // icl*28 + r
                int c = i2 - q * 28;
                int icl = q / 28;
                int r = q - icl * 28;            // 0..27
                int ic = ch * 8 + icl;
                const float* wp = &s_w1[ic * 9];
                const float* ip = &s_in[r * 30 + c];
                float v = b1[ic];                // L2-hot global (128 B total)
                v = fmaf(ip[0],  wp[0], v); v = fmaf(ip[1],  wp[1], v); v = fmaf(ip[2],  wp[2], v);
                v = fmaf(ip[30], wp[3], v); v = fmaf(ip[31], wp[4], v); v = fmaf(ip[32], wp[5], v);
                v = fmaf(ip[60], wp[6], v); v = fmaf(ip[61], wp[7], v); v = fmaf(ip[62], wp[8], v);
                s_h1[i2] = fmaxf(v, 0.f);
            }
        }
        // --- stage conv2 weights: [72][oc(64)] for this ic chunk ---
        // oc = i&63 varies per lane -> 2-way (free) LDS write; strided global
        // read of L2-hot w2 (73 KB).
        #pragma unroll
        for (int it = 0; it < 6; ++it) {
            int i = it * 832 + tid;              // 0..4607 used (72*64)
            if (i < 4608) {
                int oc = i & 63;
                int r  = i >> 6;                 // 0..71 = icl*9 + k
                s_w2c[r * 64 + oc] = w2[oc * 288 + ch * 72 + r];
            }
        }
        __syncthreads();
        if (ct < 3) conv2_accum<3>(hb, wb, acc);
        else        conv2_accum<4>(hb, wb, acc);
    }
    // --- pool 2x2 + relu -> s_out (disjoint cells per thread) ---
    #pragma unroll
    for (int o = 0; o < 4; ++o)
        #pragma unroll
        for (int c = 0; c < 4; ++c) {
            if (c < TCp) {
                float m = fmaxf(fmaxf(acc[o][0][2 * c], acc[o][0][2 * c + 1]),
                                fmaxf(acc[o][1][2 * c], acc[o][1][2 * c + 1]));
                s_out[(ocg * 4 + o) * 169 + pr * 13 + pc0 + c] = fmaxf(m, 0.f);
            }
        }
    __syncthreads();   // s_out complete
    // --- single dense aligned copy-out: 13*832 = 10816 exact ---
    float* gbase = hflat + (size_t)img * 10816;
    #pragma unroll
    for (int it = 0; it < 13; ++it) {
        int i = it * 832 + tid;
        gbase[i] = s_out[i];
    }
}

// ---------------- gate layer 1: logits, top-2, scatter to expert bins -------
__global__ __launch_bounds__(256)
void gate1_kernel(const float* __restrict__ hflat, const float* __restrict__ wg,
                  float* __restrict__ gt1,
                  int* __restrict__ rows_list, float* __restrict__ gate_list,
                  int* __restrict__ cnt, float* __restrict__ imp, float* __restrict__ load)
{
    __shared__ float s_imp[8], s_load[8];
    const int tid = threadIdx.x;
    if (tid < 8) { s_imp[tid] = 0.f; s_load[tid] = 0.f; }
    __syncthreads();
    const int wave = tid >> 6, lane = tid & 63;
    const int row = blockIdx.x * 4 + wave;
    const float* hp = hflat + (size_t)row * 10816;
    float acc[8] = {0.f, 0.f, 0.f, 0.f, 0.f, 0.f, 0.f, 0.f};
    for (int k0 = lane * 4; k0 < 10816; k0 += 256) {
        float4 h4 = *(const float4*)(hp + k0);
        const float4* w4 = (const float4*)(wg + (size_t)k0 * 8);
        float hv[4] = {h4.x, h4.y, h4.z, h4.w};
        #pragma unroll
        for (int j = 0; j < 4; j++) {
            float4 wa = w4[2 * j], wb = w4[2 * j + 1];
            acc[0] = fmaf(hv[j], wa.x, acc[0]); acc[1] = fmaf(hv[j], wa.y, acc[1]);
            acc[2] = fmaf(hv[j], wa.z, acc[2]); acc[3] = fmaf(hv[j], wa.w, acc[3]);
            acc[4] = fmaf(hv[j], wb.x, acc[4]); acc[5] = fmaf(hv[j], wb.y, acc[5]);
            acc[6] = fmaf(hv[j], wb.z, acc[6]); acc[7] = fmaf(hv[j], wb.w, acc[7]);
        }
    }
    #pragma unroll
    for (int e = 0; e < 8; e++)
        #pragma unroll
        for (int off = 32; off > 0; off >>= 1)
            acc[e] += __shfl_down(acc[e], off, 64);
    if (lane == 0) {
        int i0 = 0; float v0 = acc[0];
        #pragma unroll
        for (int e = 1; e < 8; e++) if (acc[e] > v0) { v0 = acc[e]; i0 = e; }
        int i1 = -1; float v1 = -1e30f;
        #pragma unroll
        for (int e = 0; e < 8; e++) if (e != i0 && acc[e] > v1) { v1 = acc[e]; i1 = e; }
        float ex = expf(v1 - v0);
        float g0 = 1.f / (1.f + ex);
        float g1 = ex / (1.f + ex);
        float* gp = gt1 + (size_t)row * 8;
        #pragma unroll
        for (int e = 0; e < 8; e++) gp[e] = 0.f;
        gp[i0] = g0; gp[i1] = g1;
        atomicAdd(&s_imp[i0], g0); atomicAdd(&s_imp[i1], g1);
        atomicAdd(&s_load[i0], 1.f); atomicAdd(&s_load[i1], 1.f);
        int p0 = atomicAdd(&cnt[i0], 1);
        rows_list[i0 * 4096 + p0] = row * 2 + 0; gate_list[i0 * 4096 + p0] = g0;
        int p1 = atomicAdd(&cnt[i1], 1);
        rows_list[i1 * 4096 + p1] = row * 2 + 1; gate_list[i1 * 4096 + p1] = g1;
    }
    __syncthreads();
    if (tid < 8) { atomicAdd(&imp[tid], s_imp[tid]); atomicAdd(&load[tid], s_load[tid]); }
}

// ---------------- MoE1 expert GEMM: M=64, N=128, K-split x2 -----------------
__global__ __launch_bounds__(256)
void moe1_gemm(const float* __restrict__ hflat, const float* __restrict__ W1,
               const float* __restrict__ b1g,
               const int* __restrict__ rows_list, const float* __restrict__ gate_list,
               const int* __restrict__ cnt, float* __restrict__ h2quad)
{
    const int e  = blockIdx.x;
    const int t  = blockIdx.y >> 1;
    const int kh = blockIdx.y & 1;
    const int n = cnt[e];
    if (t * 64 >= n) return;
    __shared__ float sA[32][68];     // [k][m] pad 68
    __shared__ float sB[32][132];    // [k][n] pad 132
    __shared__ int   s_rows[64];
    __shared__ float s_gate[64];
    const int tid = threadIdx.x;
    const int mr = (n - t * 64 < 64) ? (n - t * 64) : 64;
    if (tid < 64) {
        int idx = t * 64 + ((tid < mr) ? tid : 0);
        s_rows[tid] = rows_list[e * 4096 + idx];
        s_gate[tid] = (tid < mr) ? gate_list[e * 4096 + t * 64 + tid] : 0.f;
    }
    __syncthreads();
    float acc[8][4];
    #pragma unroll
    for (int i = 0; i < 8; i++)
        #pragma unroll
        for (int j = 0; j < 4; j++) acc[i][j] = 0.f;
    const int tm = tid >> 5;            // 0..7 -> rows tm*8..+7
    const int tn = tid & 31;            // cols tn*4..+3
    const float* Wb = W1 + (size_t)e * 10816 * 128;
    const int ar = tid >> 2;            // 0..63
    const int ak = (tid & 3) * 8;       // 0,8,16,24
    const int bk = tid >> 3;            // 0..31
    const int bn = (tid & 7) * 16;
    const int kbase = kh * 5408;
    const float* agp = hflat + (size_t)(s_rows[ar] >> 1) * 10816 + kbase;
    for (int k0 = 0; k0 < 5408; k0 += 32) {
        float4 a0 = *(const float4*)(agp + k0 + ak);
        float4 a1 = *(const float4*)(agp + k0 + ak + 4);
        const float4* bsrc = (const float4*)(Wb + (size_t)(kbase + k0 + bk) * 128 + bn);
        float4 b0 = bsrc[0], b1v = bsrc[1], b2v = bsrc[2], b3v = bsrc[3];
        __syncthreads();
        sA[ak + 0][ar] = a0.x; sA[ak + 1][ar] = a0.y; sA[ak + 2][ar] = a0.z; sA[ak + 3][ar] = a0.w;
        sA[ak + 4][ar] = a1.x; sA[ak + 5][ar] = a1.y; sA[ak + 6][ar] = a1.z; sA[ak + 7][ar] = a1.w;
        *(float4*)&sB[bk][bn + 0]  = b0; *(float4*)&sB[bk][bn + 4]  = b1v;
        *(float4*)&sB[bk][bn + 8]  = b2v; *(float4*)&sB[bk][bn + 12] = b3v;
        __syncthreads();
        #pragma unroll
        for (int k = 0; k < 32; k++) {
            float4 av0 = *(const float4*)&sA[k][tm * 8];
            float4 av1 = *(const float4*)&sA[k][tm * 8 + 4];
            float4 bv  = *(const float4*)&sB[k][tn * 4];
            acc[0][0] = fmaf(av0.x, bv.x, acc[0][0]); acc[0][1] = fmaf(av0.x, bv.y, acc[0][1]);
            acc[0][2] = fmaf(av0.x, bv.z, acc[0][2]); acc[0][3] = fmaf(av0.x, bv.w, acc[0][3]);
            acc[1][0] = fmaf(av0.y, bv.x, acc[1][0]); acc[1][1] = fmaf(av0.y, bv.y, acc[1][1]);
            acc[1][2] = fmaf(av0.y, bv.z, acc[1][2]); acc[1][3] = fmaf(av0.y, bv.w, acc[1][3]);
            acc[2][0] = fmaf(av0.z, bv.x, acc[2][0]); acc[2][1] = fmaf(av0.z, bv.y, acc[2][1]);
            acc[2][2] = fmaf(av0.z, bv.z, acc[2][2]); acc[2][3] = fmaf(av0.z, bv.w, acc[2][3]);
            acc[3][0] = fmaf(av0.w, bv.x, acc[3][0]); acc[3][1] = fmaf(av0.w, bv.y, acc[3][1]);
            acc[3][2] = fmaf(av0.w, bv.z, acc[3][2]); acc[3][3] = fmaf(av0.w, bv.w, acc[3][3]);
            acc[4][0] = fmaf(av1.x, bv.x, acc[4][0]); acc[4][1] = fmaf(av1.x, bv.y, acc[4][1]);
            acc[4][2] = fmaf(av1.x, bv.z, acc[4][2]); acc[4][3] = fmaf(av1.x, bv.w, acc[4][3]);
            acc[5][0] = fmaf(av1.y, bv.x, acc[5][0]); acc[5][1] = fmaf(av1.y, bv.y, acc[5][1]);
            acc[5][2] = fmaf(av1.y, bv.z, acc[5][2]); acc[5][3] = fmaf(av1.y, bv.w, acc[5][3]);
            acc[6][0] = fmaf(av1.z, bv.x, acc[6][0]); acc[6][1] = fmaf(av1.z, bv.y, acc[6][1]);
            acc[6][2] = fmaf(av1.z, bv.z, acc[6][2]); acc[6][3] = fmaf(av1.z, bv.w, acc[6][3]);
            acc[7][0] = fmaf(av1.w, bv.x, acc[7][0]); acc[7][1] = fmaf(av1.w, bv.y, acc[7][1]);
            acc[7][2] = fmaf(av1.w, bv.z, acc[7][2]); acc[7][3] = fmaf(av1.w, bv.w, acc[7][3]);
        }
    }
    const float* b1e = b1g + e * 128;
    float bx = (kh == 0) ? b1e[tn * 4 + 0] : 0.f;
    float by = (kh == 0) ? b1e[tn * 4 + 1] : 0.f;
    float bz = (kh == 0) ? b1e[tn * 4 + 2] : 0.f;
    float bw = (kh == 0) ? b1e[tn * 4 + 3] : 0.f;
    #pragma unroll
    for (int i = 0; i < 8; i++) {
        int m = tm * 8 + i;
        if (m < mr) {
            float g = s_gate[m];
            int rs = s_rows[m];
            float4 o;
            o.x = (acc[i][0] + bx) * g;
            o.y = (acc[i][1] + by) * g;
            o.z = (acc[i][2] + bz) * g;
            o.w = (acc[i][3] + bw) * g;
            *(float4*)(h2quad + ((size_t)rs * 2 + kh) * 128 + tn * 4) = o;
        }
    }
}

// ---------------- MoE2 head + log_softmax ----------------------------------
__global__ __launch_bounds__(64)
void moe2_head(const float* __restrict__ h2quad, const float* __restrict__ wg2,
               const float* __restrict__ W2, const float* __restrict__ b2,
               float* __restrict__ gt2, float* __restrict__ logp,
               float* __restrict__ imp2, float* __restrict__ load2)
{
    __shared__ float s_wg[128 * 8];
    __shared__ float s_W2[8 * 128 * 10];
    __shared__ float s_b2[80];
    __shared__ float s_imp[8], s_load[8];
    const int tid = threadIdx.x;
    for (int i = tid; i < 1024; i += 64) s_wg[i] = wg2[i];
    for (int i = tid; i < 10240; i += 64) s_W2[i] = W2[i];
    for (int i = tid; i < 80; i += 64) s_b2[i] = b2[i];
    if (tid < 8) { s_imp[tid] = 0.f; s_load[tid] = 0.f; }
    __syncthreads();
    const int row = blockIdx.x * 64 + tid;
    float h[128];
    const float* p0 = h2quad + (size_t)row * 512;
    #pragma unroll
    for (int i = 0; i < 128; i += 4) {
        float4 a = *(const float4*)(p0 + i);
        float4 b = *(const float4*)(p0 + 128 + i);
        float4 c = *(const float4*)(p0 + 256 + i);
        float4 d = *(const float4*)(p0 + 384 + i);
        h[i + 0] = fmaxf(a.x + b.x + c.x + d.x, 0.f);
        h[i + 1] = fmaxf(a.y + b.y + c.y + d.y, 0.f);
        h[i + 2] = fmaxf(a.z + b.z + c.z + d.z, 0.f);
        h[i + 3] = fmaxf(a.w + b.w + c.w + d.w, 0.f);
    }
    float lg[8] = {0.f, 0.f, 0.f, 0.f, 0.f, 0.f, 0.f, 0.f};
    #pragma unroll
    for (int k = 0; k < 128; k++) {
        float hv = h[k];
        #pragma unroll
        for (int e = 0; e < 8; e++) lg[e] = fmaf(hv, s_wg[k * 8 + e], lg[e]);
    }
    int i0 = 0; float v0 = lg[0];
    #pragma unroll
    for (int e = 1; e < 8; e++) if (lg[e] > v0) { v0 = lg[e]; i0 = e; }
    int i1 = -1; float v1 = -1e30f;
    #pragma unroll
    for (int e = 0; e < 8; e++) if (e != i0 && lg[e] > v1) { v1 = lg[e]; i1 = e; }
    float ex = expf(v1 - v0);
    float g0 = 1.f / (1.f + ex);
    float g1 = ex / (1.f + ex);
    float* gp = gt2 + (size_t)row * 8;
    #pragma unroll
    for (int e = 0; e < 8; e++) gp[e] = 0.f;
    gp[i0] = g0; gp[i1] = g1;
    atomicAdd(&s_imp[i0], g0); atomicAdd(&s_imp[i1], g1);
    atomicAdd(&s_load[i0], 1.f); atomicAdd(&s_load[i1], 1.f);
    float y[10];
    #pragma unroll
    for (int nn = 0; nn < 10; nn++)
        y[nn] = g0 * s_b2[i0 * 10 + nn] + g1 * s_b2[i1 * 10 + nn];
    #pragma unroll
    for (int k = 0; k < 128; k++) {
        float a = g0 * h[k];
        float b = g1 * h[k];
        const float* w0p = &s_W2[(i0 * 128 + k) * 10];
        const float* w1p = &s_W2[(i1 * 128 + k) * 10];
        #pragma unroll
        for (int nn = 0; nn < 10; nn++)
            y[nn] = fmaf(a, w0p[nn], fmaf(b, w1p[nn], y[nn]));
    }
    float m = y[0];
    #pragma unroll
    for (int nn = 1; nn < 10; nn++) m = fmaxf(m, y[nn]);
    float s = 0.f;
    #pragma unroll
    for (int nn = 0; nn < 10; nn++) s += expf(y[nn] - m);
    float ls = m + logf(s);
    float* op = logp + (size_t)row * 10;
    #pragma unroll
    for (int nn = 0; nn < 10; nn++) op[nn] = y[nn] - ls;
    __syncthreads();
    if (tid < 8) { atomicAdd(&imp2[tid], s_imp[tid]); atomicAdd(&load2[tid], s_load[tid]); }
}

// ---------------- loss ------------------------------------------------------
__device__ float cv_sq(const float* v)
{
    float m = 0.f;
    for (int i = 0; i < 8; i++) m += v[i];
    m *= 0.125f;
    float s = 0.f;
    for (int i = 0; i < 8; i++) { float d = v[i] - m; s += d * d; }
    float var = s * (1.f / 7.f);          // ddof=1
    return var / (m * m + 1e-10f);
}

__global__ void loss_kernel(const float* __restrict__ imp1, const float* __restrict__ load1,
                            const float* __restrict__ imp2, const float* __restrict__ load2,
                            float* __restrict__ out)
{
    if (threadIdx.x == 0) {
        float l = (cv_sq(imp1) + cv_sq(load1) + cv_sq(imp2) + cv_sq(load2)) * 3e-5f;
        out[0] = l;
    }
}

// ---------------------------------------------------------------------------
extern "C" void kernel_launch(void* const* d_in, const int* in_sizes, int n_in,
                              void* d_out, int out_size, void* d_ws, size_t ws_size,
                              hipStream_t stream)
{
    const float* x       = (const float*)d_in[0];
    const float* conv1_w = (const float*)d_in[1];
    const float* conv1_b = (const float*)d_in[2];
    const float* conv2_w = (const float*)d_in[3];
    const float* conv2_b = (const float*)d_in[4];
    const float* w_gate1 = (const float*)d_in[5];
    const float* W1      = (const float*)d_in[6];
    const float* b1      = (const float*)d_in[7];
    const float* w_gate2 = (const float*)d_in[8];
    const float* W2      = (const float*)d_in[9];
    const float* b2      = (const float*)d_in[10];

    char* ws = (char*)d_ws;
    float* h_flat    = (float*)(ws + OFF_HFLAT);
    float* h2quad    = (float*)(ws + OFF_H2Q);
    int*   rows_list = (int*)  (ws + OFF_ROWS);
    float* gate_list = (float*)(ws + OFF_GATES);
    int*   cnt1      = (int*)  (ws + OFF_SMALL);
    float* imp1      = (float*)(ws + OFF_SMALL) + 8;
    float* load1     = (float*)(ws + OFF_SMALL) + 16;
    float* imp2      = (float*)(ws + OFF_SMALL) + 24;
    float* load2     = (float*)(ws + OFF_SMALL) + 32;

    float* logp_out = (float*)d_out;            // [4096,10]
    float* gt1_out  = (float*)d_out + 40960;    // [4096,8]
    float* gt2_out  = (float*)d_out + 73728;    // [4096,8]
    float* loss_out = (float*)d_out + 106496;   // [1]

    hipMemsetAsync(ws + OFF_SMALL, 0, 40 * sizeof(float), stream);

    conv_fused<<<4096, 832, 0, stream>>>(x, conv1_w, conv1_b, conv2_w, conv2_b, h_flat);
    gate1_kernel<<<1024, 256, 0, stream>>>(h_flat, w_gate1, gt1_out,
                                           rows_list, gate_list, cnt1, imp1, load1);
    moe1_gemm<<<dim3(8, 128), 256, 0, stream>>>(h_flat, W1, b1, rows_list, gate_list,
                                                cnt1, h2quad);
    moe2_head<<<64, 64, 0, stream>>>(h2quad, w_gate2, W2, b2,
                                     gt2_out, logp_out, imp2, load2);
    loss_kernel<<<1, 64, 0, stream>>>(imp1, load1, imp2, load2, loss_out);
}

// Round 14
// 3772.558 us; speedup vs baseline: 1.0004x; 1.0004x over previous
//
#include <hip/hip_runtime.h>
#include <cstdint>
#include <cstddef>

// ---------------------------------------------------------------------------
//   x:[4096,1,30,30] -> conv1(32,3x3)+relu -> conv2(64,3x3)+relu -> maxpool2
//   -> flatten [4096,10816] -> MoE(top2, 8 experts, 10816->128) -> relu
//   -> MoE(top2, 8 experts, 128->10) -> log_softmax
//   outputs: logp[4096,10], gt_l1[4096,8], gt_l2[4096,8], loss[1]
// ---------------------------------------------------------------------------

// ws layout (bytes)
static const size_t OFF_HFLAT = 0;                                        // 177,209,344
static const size_t OFF_H2Q   = (size_t)4096 * 10816 * 4;                 // 4096*4*128*4 = 8,388,608
static const size_t OFF_ROWS  = OFF_H2Q + (size_t)4096 * 4 * 128 * 4;     // 8*4096*4
static const size_t OFF_GATES = OFF_ROWS + (size_t)8 * 4096 * 4;          // 8*4096*4
static const size_t OFF_SMALL = OFF_GATES + (size_t)8 * 4096 * 4;         // 40*4
// small: [0..7] cnt(int) | [8..15] imp1 | [16..23] load1 | [24..31] imp2 | [32..39] load2

// ---------------- fused conv1 -> conv2 -> maxpool ---------------------------
// One 832-thread block per image (grid 4096), all 64 oc, SINGLE PASS.
// REFINED LAUNCH-BOUNDS LAW (rounds 0-13): compiler caps VGPR at
// 512 / ceil(w * waves_per_block / 4):
//   (512,2) -> 4/SIMD -> 128 (spill-free, traffic ideal: rounds 7/9/11)
//   (512,4) -> 8/SIMD -> 64  (spills, multi-GB traffic: round 8)
//   (832,2) -> 7/SIMD -> 64  (spills: round 13 -- FETCH 1.4 GB, WRITE 2.1 GB)
// ROUND 14: (832,1) -> 13 waves/block forces max 4 waves on a SIMD ->
// compiler must cap at 128 = the proven spill-free allocation, with the
// full 13-wave block resident (vs 8 waves at 512 threads).
// Thread map: ct = tid/208 (col quarter; only wave 9 straddles TCp 3/4),
// pr = (tid%208)>>4 in 0..12 exact, ocg = tid&15 (oc ocg*4..+3).
// vs round 7's two-band: conv2 issue 832 vs 1024 thread-streams (-19%),
// conv1 staging 28 vs 36 rows, barriers 10 vs 17, 13 vs 8 waves resident.
// Inner loop = round 7's exact proven conv2_accum (4 row buffers, unroll 2).
// Epilogue: full pooled image staged in s_out, single dense aligned copy-out
// (13*832 = 10816 exact).

template<int PC>
__device__ __forceinline__ void ld_row(float* r, const float* __restrict__ p)
{
    #pragma unroll
    for (int c = 0; c < PC; c += 2) {
        float2 t = *(const float2*)(p + c);
        r[c] = t.x; r[c + 1] = t.y;
    }
}

template<int TC>
__device__ __forceinline__ void fma_ky(float acc[4][2][8], const float* ra, const float* rb,
                                       const float* __restrict__ wk)
{
    #pragma unroll
    for (int kx = 0; kx < 3; ++kx) {
        float4 w = *(const float4*)(wk + kx * 64);   // [kk][oc(64)]
        #pragma unroll
        for (int c = 0; c < 2 * TC; ++c) {
            float ia = ra[c + kx], ib = rb[c + kx];
            acc[0][0][c] = fmaf(ia, w.x, acc[0][0][c]);
            acc[1][0][c] = fmaf(ia, w.y, acc[1][0][c]);
            acc[2][0][c] = fmaf(ia, w.z, acc[2][0][c]);
            acc[3][0][c] = fmaf(ia, w.w, acc[3][0][c]);
            acc[0][1][c] = fmaf(ib, w.x, acc[0][1][c]);
            acc[1][1][c] = fmaf(ib, w.y, acc[1][1][c]);
            acc[2][1][c] = fmaf(ib, w.z, acc[2][1][c]);
            acc[3][1][c] = fmaf(ib, w.w, acc[3][1][c]);
        }
    }
}

template<int TC>
__device__ __forceinline__ void conv2_accum(const float* __restrict__ hb,
                                            const float* __restrict__ wb,
                                            float acc[4][2][8])
{
    #pragma unroll 2
    for (int icl = 0; icl < 8; ++icl) {
        const float* h = hb + icl * 784;   // [icl][r(28)][c(28)]
        const float* w = wb + icl * 576;   // [icl][kk 0..8][64]
        float r0[2 * TC + 2], r1[2 * TC + 2], r2[2 * TC + 2], r3[2 * TC + 2];
        ld_row<2 * TC + 2>(r0, h);
        ld_row<2 * TC + 2>(r1, h + 28);
        fma_ky<TC>(acc, r0, r1, w);
        ld_row<2 * TC + 2>(r2, h + 56);
        fma_ky<TC>(acc, r1, r2, w + 192);
        ld_row<2 * TC + 2>(r3, h + 84);
        fma_ky<TC>(acc, r2, r3, w + 384);
    }
}

__global__ __launch_bounds__(832, 1)
void conv_fused(const float* __restrict__ x,
                const float* __restrict__ w1, const float* __restrict__ b1,
                const float* __restrict__ w2, const float* __restrict__ b2,
                float* __restrict__ hflat)
{
    __shared__ float s_in[900];      // full image [30][30], staged once
    __shared__ float s_w1[288];
    __shared__ float s_h1[6272];     // [icl(8)][r(28)][c(28)] chunk of conv1 out
    __shared__ float s_w2c[4608];    // [kk(72)=icl*9+k][oc(64)] current ic-chunk
    __shared__ float s_out[10816];   // full pooled image [64 oc][13][13]
    // total: 900+288+6272+4608+10816 = 22,884 floats = 91,536 B (1 block/CU)

    const int img = blockIdx.x, tid = threadIdx.x;

    const float* xin = x + (size_t)img * 900;
    for (int i = tid; i < 900; i += 832) s_in[i] = xin[i];
    if (tid < 288) s_w1[tid] = w1[tid];
    __syncthreads();   // orders preamble staging with all later readers

    const int ct  = tid / 208;            // 0..3 col quarter (208-thread chunks)
    const int rem = tid - ct * 208;
    const int pr  = rem >> 4;             // 0..12 pooled row (exact, no mask)
    const int ocg = tid & 15;             // 0..15 -> oc ocg*4..+3 (208%16==0)
    const int c0  = ct * 6;               // pre-col start: 0,6,12,18
    const int pc0 = ct * 3;               // pooled-col start
    const int TCp = (ct < 3) ? 3 : 4;     // pooled cols this thread

    const float* hb = s_h1 + 2 * pr * 28 + c0;   // pre-rows 2pr..2pr+3
    const float* wb = s_w2c + ocg * 4;

    float acc[4][2][8];
    #pragma unroll
    for (int o = 0; o < 4; ++o) {
        float bb = b2[ocg * 4 + o];              // L2-hot global (256 B total)
        #pragma unroll
        for (int r = 0; r < 2; ++r)
            #pragma unroll
            for (int c = 0; c < 8; ++c) acc[o][r][c] = bb;
    }

    #pragma unroll 1
    for (int ch = 0; ch < 4; ++ch) {             // 4 chunks x 8 ic
        __syncthreads();   // previous compute done before restaging s_h1/s_w2c
        // --- stage conv1: rows 0..27, cols 0..27, ic chunk ch*8..+7 ---
        #pragma unroll
        for (int it = 0; it < 8; ++it) {
            int i2 = it * 832 + tid;             // 0..6271 used (8*28*28)
            if (i2 < 6272) {
                int q = i2 / 28;                 // icl*28 + r
                int c = i2 - q * 28;
                int icl = q / 28;
                int r = q - icl * 28;            // 0..27
                int ic = ch * 8 + icl;
                const float* wp = &s_w1[ic * 9];
                const float* ip = &s_in[r * 30 + c];
                float v = b1[ic];                // L2-hot global (128 B total)
                v = fmaf(ip[0],  wp[0], v); v = fmaf(ip[1],  wp[1], v); v = fmaf(ip[2],  wp[2], v);
                v = fmaf(ip[30], wp[3], v); v = fmaf(ip[31], wp[4], v); v = fmaf(ip[32], wp[5], v);
                v = fmaf(ip[60], wp[6], v); v = fmaf(ip[61], wp[7], v); v = fmaf(ip[62], wp[8], v);
                s_h1[i2] = fmaxf(v, 0.f);
            }
        }
        // --- stage conv2 weights: [72][oc(64)] for this ic chunk ---
        // oc = i&63 varies per lane -> 2-way (free) LDS write; strided global
        // read of L2-hot w2 (73 KB).
        #pragma unroll
        for (int it = 0; it < 6; ++it) {
            int i = it * 832 + tid;              // 0..4607 used (72*64)
            if (i < 4608) {
                int oc = i & 63;
                int r  = i >> 6;                 // 0..71 = icl*9 + k
                s_w2c[r * 64 + oc] = w2[oc * 288 + ch * 72 + r];
            }
        }
        __syncthreads();
        if (ct < 3) conv2_accum<3>(hb, wb, acc);
        else        conv2_accum<4>(hb, wb, acc);
    }
    // --- pool 2x2 + relu -> s_out (disjoint cells per thread) ---
    #pragma unroll
    for (int o = 0; o < 4; ++o)
        #pragma unroll
        for (int c = 0; c < 4; ++c) {
            if (c < TCp) {
                float m = fmaxf(fmaxf(acc[o][0][2 * c], acc[o][0][2 * c + 1]),
                                fmaxf(acc[o][1][2 * c], acc[o][1][2 * c + 1]));
                s_out[(ocg * 4 + o) * 169 + pr * 13 + pc0 + c] = fmaxf(m, 0.f);
            }
        }
    __syncthreads();   // s_out complete
    // --- single dense aligned copy-out: 13*832 = 10816 exact ---
    float* gbase = hflat + (size_t)img * 10816;
    #pragma unroll
    for (int it = 0; it < 13; ++it) {
        int i = it * 832 + tid;
        gbase[i] = s_out[i];
    }
}

// ---------------- gate layer 1: logits, top-2, scatter to expert bins -------
__global__ __launch_bounds__(256)
void gate1_kernel(const float* __restrict__ hflat, const float* __restrict__ wg,
                  float* __restrict__ gt1,
                  int* __restrict__ rows_list, float* __restrict__ gate_list,
                  int* __restrict__ cnt, float* __restrict__ imp, float* __restrict__ load)
{
    __shared__ float s_imp[8], s_load[8];
    const int tid = threadIdx.x;
    if (tid < 8) { s_imp[tid] = 0.f; s_load[tid] = 0.f; }
    __syncthreads();
    const int wave = tid >> 6, lane = tid & 63;
    const int row = blockIdx.x * 4 + wave;
    const float* hp = hflat + (size_t)row * 10816;
    float acc[8] = {0.f, 0.f, 0.f, 0.f, 0.f, 0.f, 0.f, 0.f};
    for (int k0 = lane * 4; k0 < 10816; k0 += 256) {
        float4 h4 = *(const float4*)(hp + k0);
        const float4* w4 = (const float4*)(wg + (size_t)k0 * 8);
        float hv[4] = {h4.x, h4.y, h4.z, h4.w};
        #pragma unroll
        for (int j = 0; j < 4; j++) {
            float4 wa = w4[2 * j], wb = w4[2 * j + 1];
            acc[0] = fmaf(hv[j], wa.x, acc[0]); acc[1] = fmaf(hv[j], wa.y, acc[1]);
            acc[2] = fmaf(hv[j], wa.z, acc[2]); acc[3] = fmaf(hv[j], wa.w, acc[3]);
            acc[4] = fmaf(hv[j], wb.x, acc[4]); acc[5] = fmaf(hv[j], wb.y, acc[5]);
            acc[6] = fmaf(hv[j], wb.z, acc[6]); acc[7] = fmaf(hv[j], wb.w, acc[7]);
        }
    }
    #pragma unroll
    for (int e = 0; e < 8; e++)
        #pragma unroll
        for (int off = 32; off > 0; off >>= 1)
            acc[e] += __shfl_down(acc[e], off, 64);
    if (lane == 0) {
        int i0 = 0; float v0 = acc[0];
        #pragma unroll
        for (int e = 1; e < 8; e++) if (acc[e] > v0) { v0 = acc[e]; i0 = e; }
        int i1 = -1; float v1 = -1e30f;
        #pragma unroll
        for (int e = 0; e < 8; e++) if (e != i0 && acc[e] > v1) { v1 = acc[e]; i1 = e; }
        float ex = expf(v1 - v0);
        float g0 = 1.f / (1.f + ex);
        float g1 = ex / (1.f + ex);
        float* gp = gt1 + (size_t)row * 8;
        #pragma unroll
        for (int e = 0; e < 8; e++) gp[e] = 0.f;
        gp[i0] = g0; gp[i1] = g1;
        atomicAdd(&s_imp[i0], g0); atomicAdd(&s_imp[i1], g1);
        atomicAdd(&s_load[i0], 1.f); atomicAdd(&s_load[i1], 1.f);
        int p0 = atomicAdd(&cnt[i0], 1);
        rows_list[i0 * 4096 + p0] = row * 2 + 0; gate_list[i0 * 4096 + p0] = g0;
        int p1 = atomicAdd(&cnt[i1], 1);
        rows_list[i1 * 4096 + p1] = row * 2 + 1; gate_list[i1 * 4096 + p1] = g1;
    }
    __syncthreads();
    if (tid < 8) { atomicAdd(&imp[tid], s_imp[tid]); atomicAdd(&load[tid], s_load[tid]); }
}

// ---------------- MoE1 expert GEMM: M=64, N=128, K-split x2 -----------------
__global__ __launch_bounds__(256)
void moe1_gemm(const float* __restrict__ hflat, const float* __restrict__ W1,
               const float* __restrict__ b1g,
               const int* __restrict__ rows_list, const float* __restrict__ gate_list,
               const int* __restrict__ cnt, float* __restrict__ h2quad)
{
    const int e  = blockIdx.x;
    const int t  = blockIdx.y >> 1;
    const int kh = blockIdx.y & 1;
    const int n = cnt[e];
    if (t * 64 >= n) return;
    __shared__ float sA[32][68];     // [k][m] pad 68
    __shared__ float sB[32][132];    // [k][n] pad 132
    __shared__ int   s_rows[64];
    __shared__ float s_gate[64];
    const int tid = threadIdx.x;
    const int mr = (n - t * 64 < 64) ? (n - t * 64) : 64;
    if (tid < 64) {
        int idx = t * 64 + ((tid < mr) ? tid : 0);
        s_rows[tid] = rows_list[e * 4096 + idx];
        s_gate[tid] = (tid < mr) ? gate_list[e * 4096 + t * 64 + tid] : 0.f;
    }
    __syncthreads();
    float acc[8][4];
    #pragma unroll
    for (int i = 0; i < 8; i++)
        #pragma unroll
        for (int j = 0; j < 4; j++) acc[i][j] = 0.f;
    const int tm = tid >> 5;            // 0..7 -> rows tm*8..+7
    const int tn = tid & 31;            // cols tn*4..+3
    const float* Wb = W1 + (size_t)e * 10816 * 128;
    const int ar = tid >> 2;            // 0..63
    const int ak = (tid & 3) * 8;       // 0,8,16,24
    const int bk = tid >> 3;            // 0..31
    const int bn = (tid & 7) * 16;
    const int kbase = kh * 5408;
    const float* agp = hflat + (size_t)(s_rows[ar] >> 1) * 10816 + kbase;
    for (int k0 = 0; k0 < 5408; k0 += 32) {
        float4 a0 = *(const float4*)(agp + k0 + ak);
        float4 a1 = *(const float4*)(agp + k0 + ak + 4);
        const float4* bsrc = (const float4*)(Wb + (size_t)(kbase + k0 + bk) * 128 + bn);
        float4 b0 = bsrc[0], b1v = bsrc[1], b2v = bsrc[2], b3v = bsrc[3];
        __syncthreads();
        sA[ak + 0][ar] = a0.x; sA[ak + 1][ar] = a0.y; sA[ak + 2][ar] = a0.z; sA[ak + 3][ar] = a0.w;
        sA[ak + 4][ar] = a1.x; sA[ak + 5][ar] = a1.y; sA[ak + 6][ar] = a1.z; sA[ak + 7][ar] = a1.w;
        *(float4*)&sB[bk][bn + 0]  = b0; *(float4*)&sB[bk][bn + 4]  = b1v;
        *(float4*)&sB[bk][bn + 8]  = b2v; *(float4*)&sB[bk][bn + 12] = b3v;
        __syncthreads();
        #pragma unroll
        for (int k = 0; k < 32; k++) {
            float4 av0 = *(const float4*)&sA[k][tm * 8];
            float4 av1 = *(const float4*)&sA[k][tm * 8 + 4];
            float4 bv  = *(const float4*)&sB[k][tn * 4];
            acc[0][0] = fmaf(av0.x, bv.x, acc[0][0]); acc[0][1] = fmaf(av0.x, bv.y, acc[0][1]);
            acc[0][2] = fmaf(av0.x, bv.z, acc[0][2]); acc[0][3] = fmaf(av0.x, bv.w, acc[0][3]);
            acc[1][0] = fmaf(av0.y, bv.x, acc[1][0]); acc[1][1] = fmaf(av0.y, bv.y, acc[1][1]);
            acc[1][2] = fmaf(av0.y, bv.z, acc[1][2]); acc[1][3] = fmaf(av0.y, bv.w, acc[1][3]);
            acc[2][0] = fmaf(av0.z, bv.x, acc[2][0]); acc[2][1] = fmaf(av0.z, bv.y, acc[2][1]);
            acc[2][2] = fmaf(av0.z, bv.z, acc[2][2]); acc[2][3] = fmaf(av0.z, bv.w, acc[2][3]);
            acc[3][0] = fmaf(av0.w, bv.x, acc[3][0]); acc[3][1] = fmaf(av0.w, bv.y, acc[3][1]);
            acc[3][2] = fmaf(av0.w, bv.z, acc[3][2]); acc[3][3] = fmaf(av0.w, bv.w, acc[3][3]);
            acc[4][0] = fmaf(av1.x, bv.x, acc[4][0]); acc[4][1] = fmaf(av1.x, bv.y, acc[4][1]);
            acc[4][2] = fmaf(av1.x, bv.z, acc[4][2]); acc[4][3] = fmaf(av1.x, bv.w, acc[4][3]);
            acc[5][0] = fmaf(av1.y, bv.x, acc[5][0]); acc[5][1] = fmaf(av1.y, bv.y, acc[5][1]);
            acc[5][2] = fmaf(av1.y, bv.z, acc[5][2]); acc[5][3] = fmaf(av1.y, bv.w, acc[5][3]);
            acc[6][0] = fmaf(av1.z, bv.x, acc[6][0]); acc[6][1] = fmaf(av1.z, bv.y, acc[6][1]);
            acc[6][2] = fmaf(av1.z, bv.z, acc[6][2]); acc[6][3] = fmaf(av1.z, bv.w, acc[6][3]);
            acc[7][0] = fmaf(av1.w, bv.x, acc[7][0]); acc[7][1] = fmaf(av1.w, bv.y, acc[7][1]);
            acc[7][2] = fmaf(av1.w, bv.z, acc[7][2]); acc[7][3] = fmaf(av1.w, bv.w, acc[7][3]);
        }
    }
    const float* b1e = b1g + e * 128;
    float bx = (kh == 0) ? b1e[tn * 4 + 0] : 0.f;
    float by = (kh == 0) ? b1e[tn * 4 + 1] : 0.f;
    float bz = (kh == 0) ? b1e[tn * 4 + 2] : 0.f;
    float bw = (kh == 0) ? b1e[tn * 4 + 3] : 0.f;
    #pragma unroll
    for (int i = 0; i < 8; i++) {
        int m = tm * 8 + i;
        if (m < mr) {
            float g = s_gate[m];
            int rs = s_rows[m];
            float4 o;
            o.x = (acc[i][0] + bx) * g;
            o.y = (acc[i][1] + by) * g;
            o.z = (acc[i][2] + bz) * g;
            o.w = (acc[i][3] + bw) * g;
            *(float4*)(h2quad + ((size_t)rs * 2 + kh) * 128 + tn * 4) = o;
        }
    }
}

// ---------------- MoE2 head + log_softmax ----------------------------------
__global__ __launch_bounds__(64)
void moe2_head(const float* __restrict__ h2quad, const float* __restrict__ wg2,
               const float* __restrict__ W2, const float* __restrict__ b2,
               float* __restrict__ gt2, float* __restrict__ logp,
               float* __restrict__ imp2, float* __restrict__ load2)
{
    __shared__ float s_wg[128 * 8];
    __shared__ float s_W2[8 * 128 * 10];
    __shared__ float s_b2[80];
    __shared__ float s_imp[8], s_load[8];
    const int tid = threadIdx.x;
    for (int i = tid; i < 1024; i += 64) s_wg[i] = wg2[i];
    for (int i = tid; i < 10240; i += 64) s_W2[i] = W2[i];
    for (int i = tid; i < 80; i += 64) s_b2[i] = b2[i];
    if (tid < 8) { s_imp[tid] = 0.f; s_load[tid] = 0.f; }
    __syncthreads();
    const int row = blockIdx.x * 64 + tid;
    float h[128];
    const float* p0 = h2quad + (size_t)row * 512;
    #pragma unroll
    for (int i = 0; i < 128; i += 4) {
        float4 a = *(const float4*)(p0 + i);
        float4 b = *(const float4*)(p0 + 128 + i);
        float4 c = *(const float4*)(p0 + 256 + i);
        float4 d = *(const float4*)(p0 + 384 + i);
        h[i + 0] = fmaxf(a.x + b.x + c.x + d.x, 0.f);
        h[i + 1] = fmaxf(a.y + b.y + c.y + d.y, 0.f);
        h[i + 2] = fmaxf(a.z + b.z + c.z + d.z, 0.f);
        h[i + 3] = fmaxf(a.w + b.w + c.w + d.w, 0.f);
    }
    float lg[8] = {0.f, 0.f, 0.f, 0.f, 0.f, 0.f, 0.f, 0.f};
    #pragma unroll
    for (int k = 0; k < 128; k++) {
        float hv = h[k];
        #pragma unroll
        for (int e = 0; e < 8; e++) lg[e] = fmaf(hv, s_wg[k * 8 + e], lg[e]);
    }
    int i0 = 0; float v0 = lg[0];
    #pragma unroll
    for (int e = 1; e < 8; e++) if (lg[e] > v0) { v0 = lg[e]; i0 = e; }
    int i1 = -1; float v1 = -1e30f;
    #pragma unroll
    for (int e = 0; e < 8; e++) if (e != i0 && lg[e] > v1) { v1 = lg[e]; i1 = e; }
    float ex = expf(v1 - v0);
    float g0 = 1.f / (1.f + ex);
    float g1 = ex / (1.f + ex);
    float* gp = gt2 + (size_t)row * 8;
    #pragma unroll
    for (int e = 0; e < 8; e++) gp[e] = 0.f;
    gp[i0] = g0; gp[i1] = g1;
    atomicAdd(&s_imp[i0], g0); atomicAdd(&s_imp[i1], g1);
    atomicAdd(&s_load[i0], 1.f); atomicAdd(&s_load[i1], 1.f);
    float y[10];
    #pragma unroll
    for (int nn = 0; nn < 10; nn++)
        y[nn] = g0 * s_b2[i0 * 10 + nn] + g1 * s_b2[i1 * 10 + nn];
    #pragma unroll
    for (int k = 0; k < 128; k++) {
        float a = g0 * h[k];
        float b = g1 * h[k];
        const float* w0p = &s_W2[(i0 * 128 + k) * 10];
        const float* w1p = &s_W2[(i1 * 128 + k) * 10];
        #pragma unroll
        for (int nn = 0; nn < 10; nn++)
            y[nn] = fmaf(a, w0p[nn], fmaf(b, w1p[nn], y[nn]));
    }
    float m = y[0];
    #pragma unroll
    for (int nn = 1; nn < 10; nn++) m = fmaxf(m, y[nn]);
    float s = 0.f;
    #pragma unroll
    for (int nn = 0; nn < 10; nn++) s += expf(y[nn] - m);
    float ls = m + logf(s);
    float* op = logp + (size_t)row * 10;
    #pragma unroll
    for (int nn = 0; nn < 10; nn++) op[nn] = y[nn] - ls;
    __syncthreads();
    if (tid < 8) { atomicAdd(&imp2[tid], s_imp[tid]); atomicAdd(&load2[tid], s_load[tid]); }
}

// ---------------- loss ------------------------------------------------------
__device__ float cv_sq(const float* v)
{
    float m = 0.f;
    for (int i = 0; i < 8; i++) m += v[i];
    m *= 0.125f;
    float s = 0.f;
    for (int i = 0; i < 8; i++) { float d = v[i] - m; s += d * d; }
    float var = s * (1.f / 7.f);          // ddof=1
    return var / (m * m + 1e-10f);
}

__global__ void loss_kernel(const float* __restrict__ imp1, const float* __restrict__ load1,
                            const float* __restrict__ imp2, const float* __restrict__ load2,
                            float* __restrict__ out)
{
    if (threadIdx.x == 0) {
        float l = (cv_sq(imp1) + cv_sq(load1) + cv_sq(imp2) + cv_sq(load2)) * 3e-5f;
        out[0] = l;
    }
}

// ---------------------------------------------------------------------------
extern "C" void kernel_launch(void* const* d_in, const int* in_sizes, int n_in,
                              void* d_out, int out_size, void* d_ws, size_t ws_size,
                              hipStream_t stream)
{
    const float* x       = (const float*)d_in[0];
    const float* conv1_w = (const float*)d_in[1];
    const float* conv1_b = (const float*)d_in[2];
    const float* conv2_w = (const float*)d_in[3];
    const float* conv2_b = (const float*)d_in[4];
    const float* w_gate1 = (const float*)d_in[5];
    const float* W1      = (const float*)d_in[6];
    const float* b1      = (const float*)d_in[7];
    const float* w_gate2 = (const float*)d_in[8];
    const float* W2      = (const float*)d_in[9];
    const float* b2      = (const float*)d_in[10];

    char* ws = (char*)d_ws;
    float* h_flat    = (float*)(ws + OFF_HFLAT);
    float* h2quad    = (float*)(ws + OFF_H2Q);
    int*   rows_list = (int*)  (ws + OFF_ROWS);
    float* gate_list = (float*)(ws + OFF_GATES);
    int*   cnt1      = (int*)  (ws + OFF_SMALL);
    float* imp1      = (float*)(ws + OFF_SMALL) + 8;
    float* load1     = (float*)(ws + OFF_SMALL) + 16;
    float* imp2      = (float*)(ws + OFF_SMALL) + 24;
    float* load2     = (float*)(ws + OFF_SMALL) + 32;

    float* logp_out = (float*)d_out;            // [4096,10]
    float* gt1_out  = (float*)d_out + 40960;    // [4096,8]
    float* gt2_out  = (float*)d_out + 73728;    // [4096,8]
    float* loss_out = (float*)d_out + 106496;   // [1]

    hipMemsetAsync(ws + OFF_SMALL, 0, 40 * sizeof(float), stream);

    conv_fused<<<4096, 832, 0, stream>>>(x, conv1_w, conv1_b, conv2_w, conv2_b, h_flat);
    gate1_kernel<<<1024, 256, 0, stream>>>(h_flat, w_gate1, gt1_out,
                                           rows_list, gate_list, cnt1, imp1, load1);
    moe1_gemm<<<dim3(8, 128), 256, 0, stream>>>(h_flat, W1, b1, rows_list, gate_list,
                                                cnt1, h2quad);
    moe2_head<<<64, 64, 0, stream>>>(h2quad, w_gate2, W2, b2,
                                     gt2_out, logp_out, imp2, load2);
    loss_kernel<<<1, 64, 0, stream>>>(imp1, load1, imp2, load2, loss_out);
}

// Round 15
// 2899.688 us; speedup vs baseline: 1.3015x; 1.3010x over previous
//
#include <hip/hip_runtime.h>
#include <cstdint>
#include <cstddef>

// ---------------------------------------------------------------------------
//   x:[4096,1,30,30] -> conv1(32,3x3)+relu -> conv2(64,3x3)+relu -> maxpool2
//   -> flatten [4096,10816] -> MoE(top2, 8 experts, 10816->128) -> relu
//   -> MoE(top2, 8 experts, 128->10) -> log_softmax
//   outputs: logp[4096,10], gt_l1[4096,8], gt_l2[4096,8], loss[1]
// ---------------------------------------------------------------------------

// ws layout (bytes)
static const size_t OFF_HFLAT = 0;                                        // 177,209,344
static const size_t OFF_H2Q   = (size_t)4096 * 10816 * 4;                 // 4096*4*128*4 = 8,388,608
static const size_t OFF_ROWS  = OFF_H2Q + (size_t)4096 * 4 * 128 * 4;     // 8*4096*4
static const size_t OFF_GATES = OFF_ROWS + (size_t)8 * 4096 * 4;          // 8*4096*4
static const size_t OFF_SMALL = OFF_GATES + (size_t)8 * 4096 * 4;         // 40*4
// small: [0..7] cnt(int) | [8..15] imp1 | [16..23] load1 | [24..31] imp2 | [32..39] load2

// ---------------- fused conv1 -> conv2 -> maxpool ---------------------------
// ROUND 15: conv_fused reverted VERBATIM to round 7 (best verified: 1917 us,
// WRITE exactly 173 MB payload, FETCH 8 MB, VGPR 128, zero spill).
// Session-closed findings:
//  - launch bounds: (512,2) -> 128 VGPR spill-free; (*,4) -> 64 VGPR + multi-GB
//    spill traffic; 832-thread blocks clamp to 64 VGPR regardless of min-waves
//    (rounds 13/14) -> the 13-wave single-pass structure is unreachable.
//  - this kernel runs 1 block/CU at VGPR>=120 for any LDS in [64K, 92K]
//    (rounds 7/9/11); occupancy is a fixed constraint.
// grid (4096), block 512: one image per block, all 64 oc, two bands {0,5}.

template<int PC>
__device__ __forceinline__ void ld_row(float* r, const float* __restrict__ p)
{
    #pragma unroll
    for (int c = 0; c < PC; c += 2) {
        float2 t = *(const float2*)(p + c);
        r[c] = t.x; r[c + 1] = t.y;
    }
}

template<int TC>
__device__ __forceinline__ void fma_ky(float acc[4][2][8], const float* ra, const float* rb,
                                       const float* __restrict__ wk)
{
    #pragma unroll
    for (int kx = 0; kx < 3; ++kx) {
        float4 w = *(const float4*)(wk + kx * 68);   // [kk][oc pad68]
        #pragma unroll
        for (int c = 0; c < 2 * TC; ++c) {
            float ia = ra[c + kx], ib = rb[c + kx];
            acc[0][0][c] = fmaf(ia, w.x, acc[0][0][c]);
            acc[1][0][c] = fmaf(ia, w.y, acc[1][0][c]);
            acc[2][0][c] = fmaf(ia, w.z, acc[2][0][c]);
            acc[3][0][c] = fmaf(ia, w.w, acc[3][0][c]);
            acc[0][1][c] = fmaf(ib, w.x, acc[0][1][c]);
            acc[1][1][c] = fmaf(ib, w.y, acc[1][1][c]);
            acc[2][1][c] = fmaf(ib, w.z, acc[2][1][c]);
            acc[3][1][c] = fmaf(ib, w.w, acc[3][1][c]);
        }
    }
}

template<int TC>
__device__ __forceinline__ void conv2_accum(const float* __restrict__ hb,
                                            const float* __restrict__ wb,
                                            float acc[4][2][8])
{
    #pragma unroll 2
    for (int icl = 0; icl < 8; ++icl) {
        const float* h = hb + icl * 504;   // [icl][r][28] band
        const float* w = wb + icl * 612;   // [icl][kk 0..8][68]
        float r0[2 * TC + 2], r1[2 * TC + 2], r2[2 * TC + 2], r3[2 * TC + 2];
        ld_row<2 * TC + 2>(r0, h);
        ld_row<2 * TC + 2>(r1, h + 28);
        fma_ky<TC>(acc, r0, r1, w);
        ld_row<2 * TC + 2>(r2, h + 56);
        fma_ky<TC>(acc, r1, r2, w + 204);
        ld_row<2 * TC + 2>(r3, h + 84);
        fma_ky<TC>(acc, r2, r3, w + 408);
    }
}

__global__ __launch_bounds__(512, 2)
void conv_fused(const float* __restrict__ x,
                const float* __restrict__ w1, const float* __restrict__ b1,
                const float* __restrict__ w2, const float* __restrict__ b2,
                float* __restrict__ hflat)
{
    __shared__ float s_in[900];
    __shared__ float s_w1[288];
    __shared__ float s_b1[32];
    __shared__ float s_b2[64];
    __shared__ float s_h1[4032];     // [icl(8)][r(18)][c(28)] band
    __shared__ float s_w2c[4896];    // [kk(72)=icl*9+k][oc(64) pad68] current ic-chunk
    __shared__ float s_out[10816];   // full pooled image [64 oc][13][13]

    const int img = blockIdx.x, tid = threadIdx.x;

    const float* xin = x + (size_t)img * 900;
    for (int i = tid; i < 900; i += 512) s_in[i] = xin[i];
    if (tid < 288) s_w1[tid] = w1[tid];
    if (tid < 32) s_b1[tid] = b1[tid];
    if (tid < 64) s_b2[tid] = b2[tid];
    __syncthreads();   // RACE FIX: acc init below reads s_b2

    const int ct  = tid >> 7;          // 0..3 (wave-uniform: 2 waves per ct)
    const int prl = (tid >> 4) & 7;    // 0..7
    const int ocg = tid & 15;          // 0..15 -> oc ocg*4..+3
    const int c0  = ct * 6;            // pre-col start: 0,6,12,18
    const int pc0 = ct * 3;            // pooled-col start
    const int TCp = (ct < 3) ? 3 : 4;  // pooled cols this thread

    const float* hb = s_h1 + 2 * prl * 28 + c0;
    const float* wb = s_w2c + ocg * 4;

    #pragma unroll 1
    for (int band = 0; band < 2; ++band) {
        const int rb = band * 5;                 // pooled rows rb..rb+7
        float acc[4][2][8];
        #pragma unroll
        for (int o = 0; o < 4; ++o) {
            float bb = s_b2[ocg * 4 + o];
            #pragma unroll
            for (int r = 0; r < 2; ++r)
                #pragma unroll
                for (int c = 0; c < 8; ++c) acc[o][r][c] = bb;
        }
        #pragma unroll 1
        for (int ch = 0; ch < 4; ++ch) {
            __syncthreads();   // previous compute done before restaging s_h1/s_w2c
            // --- stage conv1: pre rows 2rb..2rb+17, ic chunk ch*8..+7 ---
            #pragma unroll
            for (int it = 0; it < 8; ++it) {
                int i2 = it * 512 + tid;
                if (i2 < 4032) {
                    int q = i2 / 28;           // icl*18 + r
                    int c = i2 - q * 28;
                    int icl = q / 18;
                    int r = q - icl * 18;
                    int ic = ch * 8 + icl;
                    int grow = 2 * rb + r;     // <= 27
                    const float* wp = &s_w1[ic * 9];
                    const float* ip = &s_in[grow * 30 + c];
                    float v = s_b1[ic];
                    v = fmaf(ip[0],  wp[0], v); v = fmaf(ip[1],  wp[1], v); v = fmaf(ip[2],  wp[2], v);
                    v = fmaf(ip[30], wp[3], v); v = fmaf(ip[31], wp[4], v); v = fmaf(ip[32], wp[5], v);
                    v = fmaf(ip[60], wp[6], v); v = fmaf(ip[61], wp[7], v); v = fmaf(ip[62], wp[8], v);
                    s_h1[i2] = fmaxf(v, 0.f);
                }
            }
            // --- stage conv2 weights: [72][oc(64) pad68] for this ic chunk ---
            #pragma unroll
            for (int it = 0; it < 9; ++it) {
                int i = it * 512 + tid;        // 0..4607 exact (9*512 = 4608 = 64*72)
                int oc = i / 72;
                int r = i - oc * 72;
                s_w2c[r * 68 + oc] = w2[oc * 288 + ch * 72 + r];
            }
            __syncthreads();
            if (ct < 3) conv2_accum<3>(hb, wb, acc);
            else        conv2_accum<4>(hb, wb, acc);
        }
        // --- pool 2x2 + relu -> s_out (separate array; no sync needed:
        //     next band's ch=0 __syncthreads covers the s_h1 reuse) ---
        #pragma unroll
        for (int o = 0; o < 4; ++o)
            #pragma unroll
            for (int c = 0; c < 4; ++c) {
                if (c < TCp) {
                    float m = fmaxf(fmaxf(acc[o][0][2 * c], acc[o][0][2 * c + 1]),
                                    fmaxf(acc[o][1][2 * c], acc[o][1][2 * c + 1]));
                    s_out[(ocg * 4 + o) * 169 + (rb + prl) * 13 + pc0 + c] = fmaxf(m, 0.f);
                }
            }
    }
    __syncthreads();   // s_out complete
    // --- single dense aligned copy-out: 10816 floats, base 128-aligned ---
    float* gbase = hflat + (size_t)img * 10816;
    #pragma unroll
    for (int it = 0; it < 22; ++it) {
        int i = it * 512 + tid;
        if (i < 10816) gbase[i] = s_out[i];
    }
}

// ---------------- gate layer 1: logits, top-2, scatter to expert bins -------
__global__ __launch_bounds__(256)
void gate1_kernel(const float* __restrict__ hflat, const float* __restrict__ wg,
                  float* __restrict__ gt1,
                  int* __restrict__ rows_list, float* __restrict__ gate_list,
                  int* __restrict__ cnt, float* __restrict__ imp, float* __restrict__ load)
{
    __shared__ float s_imp[8], s_load[8];
    const int tid = threadIdx.x;
    if (tid < 8) { s_imp[tid] = 0.f; s_load[tid] = 0.f; }
    __syncthreads();
    const int wave = tid >> 6, lane = tid & 63;
    const int row = blockIdx.x * 4 + wave;
    const float* hp = hflat + (size_t)row * 10816;
    float acc[8] = {0.f, 0.f, 0.f, 0.f, 0.f, 0.f, 0.f, 0.f};
    for (int k0 = lane * 4; k0 < 10816; k0 += 256) {
        float4 h4 = *(const float4*)(hp + k0);
        const float4* w4 = (const float4*)(wg + (size_t)k0 * 8);
        float hv[4] = {h4.x, h4.y, h4.z, h4.w};
        #pragma unroll
        for (int j = 0; j < 4; j++) {
            float4 wa = w4[2 * j], wb = w4[2 * j + 1];
            acc[0] = fmaf(hv[j], wa.x, acc[0]); acc[1] = fmaf(hv[j], wa.y, acc[1]);
            acc[2] = fmaf(hv[j], wa.z, acc[2]); acc[3] = fmaf(hv[j], wa.w, acc[3]);
            acc[4] = fmaf(hv[j], wb.x, acc[4]); acc[5] = fmaf(hv[j], wb.y, acc[5]);
            acc[6] = fmaf(hv[j], wb.z, acc[6]); acc[7] = fmaf(hv[j], wb.w, acc[7]);
        }
    }
    #pragma unroll
    for (int e = 0; e < 8; e++)
        #pragma unroll
        for (int off = 32; off > 0; off >>= 1)
            acc[e] += __shfl_down(acc[e], off, 64);
    if (lane == 0) {
        int i0 = 0; float v0 = acc[0];
        #pragma unroll
        for (int e = 1; e < 8; e++) if (acc[e] > v0) { v0 = acc[e]; i0 = e; }
        int i1 = -1; float v1 = -1e30f;
        #pragma unroll
        for (int e = 0; e < 8; e++) if (e != i0 && acc[e] > v1) { v1 = acc[e]; i1 = e; }
        float ex = expf(v1 - v0);
        float g0 = 1.f / (1.f + ex);
        float g1 = ex / (1.f + ex);
        float* gp = gt1 + (size_t)row * 8;
        #pragma unroll
        for (int e = 0; e < 8; e++) gp[e] = 0.f;
        gp[i0] = g0; gp[i1] = g1;
        atomicAdd(&s_imp[i0], g0); atomicAdd(&s_imp[i1], g1);
        atomicAdd(&s_load[i0], 1.f); atomicAdd(&s_load[i1], 1.f);
        int p0 = atomicAdd(&cnt[i0], 1);
        rows_list[i0 * 4096 + p0] = row * 2 + 0; gate_list[i0 * 4096 + p0] = g0;
        int p1 = atomicAdd(&cnt[i1], 1);
        rows_list[i1 * 4096 + p1] = row * 2 + 1; gate_list[i1 * 4096 + p1] = g1;
    }
    __syncthreads();
    if (tid < 8) { atomicAdd(&imp[tid], s_imp[tid]); atomicAdd(&load[tid], s_load[tid]); }
}

// ---------------- MoE1 expert GEMM: M=64, N=128, K-split x2, 512 thr --------
// ROUND 15: 512 threads (8 waves) instead of 256 (4 waves). Same 64x128 tile,
// same LDS, same traffic; each thread computes 4x4 (was 8x4). At 256 blocks
// ~ 1 block/CU this kernel ran 1 wave/SIMD -- maximally latency-exposed.
// 2 waves/SIMD doubles ds_read->FMA and global-load latency hiding.
__global__ __launch_bounds__(512)
void moe1_gemm(const float* __restrict__ hflat, const float* __restrict__ W1,
               const float* __restrict__ b1g,
               const int* __restrict__ rows_list, const float* __restrict__ gate_list,
               const int* __restrict__ cnt, float* __restrict__ h2quad)
{
    const int e  = blockIdx.x;
    const int t  = blockIdx.y >> 1;
    const int kh = blockIdx.y & 1;
    const int n = cnt[e];
    if (t * 64 >= n) return;
    __shared__ float sA[32][68];     // [k][m] pad 68
    __shared__ float sB[32][132];    // [k][n] pad 132
    __shared__ int   s_rows[64];
    __shared__ float s_gate[64];
    const int tid = threadIdx.x;
    const int mr = (n - t * 64 < 64) ? (n - t * 64) : 64;
    if (tid < 64) {
        int idx = t * 64 + ((tid < mr) ? tid : 0);
        s_rows[tid] = rows_list[e * 4096 + idx];
        s_gate[tid] = (tid < mr) ? gate_list[e * 4096 + t * 64 + tid] : 0.f;
    }
    __syncthreads();
    float acc[4][4];
    #pragma unroll
    for (int i = 0; i < 4; i++)
        #pragma unroll
        for (int j = 0; j < 4; j++) acc[i][j] = 0.f;
    const int tm = tid >> 5;            // 0..15 -> rows tm*4..+3
    const int tn = tid & 31;            // cols tn*4..+3
    const float* Wb = W1 + (size_t)e * 10816 * 128;
    const int ar = tid >> 3;            // 0..63
    const int ak = (tid & 7) * 4;       // 0,4,...,28
    const int bk = tid >> 4;            // 0..31
    const int bn = (tid & 15) * 8;      // 0,8,...,120
    const int kbase = kh * 5408;
    const float* agp = hflat + (size_t)(s_rows[ar] >> 1) * 10816 + kbase;
    for (int k0 = 0; k0 < 5408; k0 += 32) {
        float4 a0 = *(const float4*)(agp + k0 + ak);
        const float4* bsrc = (const float4*)(Wb + (size_t)(kbase + k0 + bk) * 128 + bn);
        float4 b0 = bsrc[0], b1v = bsrc[1];
        __syncthreads();
        sA[ak + 0][ar] = a0.x; sA[ak + 1][ar] = a0.y;
        sA[ak + 2][ar] = a0.z; sA[ak + 3][ar] = a0.w;
        *(float4*)&sB[bk][bn + 0] = b0; *(float4*)&sB[bk][bn + 4] = b1v;
        __syncthreads();
        #pragma unroll
        for (int k = 0; k < 32; k++) {
            float4 av = *(const float4*)&sA[k][tm * 4];
            float4 bv = *(const float4*)&sB[k][tn * 4];
            acc[0][0] = fmaf(av.x, bv.x, acc[0][0]); acc[0][1] = fmaf(av.x, bv.y, acc[0][1]);
            acc[0][2] = fmaf(av.x, bv.z, acc[0][2]); acc[0][3] = fmaf(av.x, bv.w, acc[0][3]);
            acc[1][0] = fmaf(av.y, bv.x, acc[1][0]); acc[1][1] = fmaf(av.y, bv.y, acc[1][1]);
            acc[1][2] = fmaf(av.y, bv.z, acc[1][2]); acc[1][3] = fmaf(av.y, bv.w, acc[1][3]);
            acc[2][0] = fmaf(av.z, bv.x, acc[2][0]); acc[2][1] = fmaf(av.z, bv.y, acc[2][1]);
            acc[2][2] = fmaf(av.z, bv.z, acc[2][2]); acc[2][3] = fmaf(av.z, bv.w, acc[2][3]);
            acc[3][0] = fmaf(av.w, bv.x, acc[3][0]); acc[3][1] = fmaf(av.w, bv.y, acc[3][1]);
            acc[3][2] = fmaf(av.w, bv.z, acc[3][2]); acc[3][3] = fmaf(av.w, bv.w, acc[3][3]);
        }
    }
    const float* b1e = b1g + e * 128;
    float bx = (kh == 0) ? b1e[tn * 4 + 0] : 0.f;
    float by = (kh == 0) ? b1e[tn * 4 + 1] : 0.f;
    float bz = (kh == 0) ? b1e[tn * 4 + 2] : 0.f;
    float bw = (kh == 0) ? b1e[tn * 4 + 3] : 0.f;
    #pragma unroll
    for (int i = 0; i < 4; i++) {
        int m = tm * 4 + i;
        if (m < mr) {
            float g = s_gate[m];
            int rs = s_rows[m];
            float4 o;
            o.x = (acc[i][0] + bx) * g;
            o.y = (acc[i][1] + by) * g;
            o.z = (acc[i][2] + bz) * g;
            o.w = (acc[i][3] + bw) * g;
            *(float4*)(h2quad + ((size_t)rs * 2 + kh) * 128 + tn * 4) = o;
        }
    }
}

// ---------------- MoE2 head + log_softmax ----------------------------------
__global__ __launch_bounds__(64)
void moe2_head(const float* __restrict__ h2quad, const float* __restrict__ wg2,
               const float* __restrict__ W2, const float* __restrict__ b2,
               float* __restrict__ gt2, float* __restrict__ logp,
               float* __restrict__ imp2, float* __restrict__ load2)
{
    __shared__ float s_wg[128 * 8];
    __shared__ float s_W2[8 * 128 * 10];
    __shared__ float s_b2[80];
    __shared__ float s_imp[8], s_load[8];
    const int tid = threadIdx.x;
    for (int i = tid; i < 1024; i += 64) s_wg[i] = wg2[i];
    for (int i = tid; i < 10240; i += 64) s_W2[i] = W2[i];
    for (int i = tid; i < 80; i += 64) s_b2[i] = b2[i];
    if (tid < 8) { s_imp[tid] = 0.f; s_load[tid] = 0.f; }
    __syncthreads();
    const int row = blockIdx.x * 64 + tid;
    float h[128];
    const float* p0 = h2quad + (size_t)row * 512;
    #pragma unroll
    for (int i = 0; i < 128; i += 4) {
        float4 a = *(const float4*)(p0 + i);
        float4 b = *(const float4*)(p0 + 128 + i);
        float4 c = *(const float4*)(p0 + 256 + i);
        float4 d = *(const float4*)(p0 + 384 + i);
        h[i + 0] = fmaxf(a.x + b.x + c.x + d.x, 0.f);
        h[i + 1] = fmaxf(a.y + b.y + c.y + d.y, 0.f);
        h[i + 2] = fmaxf(a.z + b.z + c.z + d.z, 0.f);
        h[i + 3] = fmaxf(a.w + b.w + c.w + d.w, 0.f);
    }
    float lg[8] = {0.f, 0.f, 0.f, 0.f, 0.f, 0.f, 0.f, 0.f};
    #pragma unroll
    for (int k = 0; k < 128; k++) {
        float hv = h[k];
        #pragma unroll
        for (int e = 0; e < 8; e++) lg[e] = fmaf(hv, s_wg[k * 8 + e], lg[e]);
    }
    int i0 = 0; float v0 = lg[0];
    #pragma unroll
    for (int e = 1; e < 8; e++) if (lg[e] > v0) { v0 = lg[e]; i0 = e; }
    int i1 = -1; float v1 = -1e30f;
    #pragma unroll
    for (int e = 0; e < 8; e++) if (e != i0 && lg[e] > v1) { v1 = lg[e]; i1 = e; }
    float ex = expf(v1 - v0);
    float g0 = 1.f / (1.f + ex);
    float g1 = ex / (1.f + ex);
    float* gp = gt2 + (size_t)row * 8;
    #pragma unroll
    for (int e = 0; e < 8; e++) gp[e] = 0.f;
    gp[i0] = g0; gp[i1] = g1;
    atomicAdd(&s_imp[i0], g0); atomicAdd(&s_imp[i1], g1);
    atomicAdd(&s_load[i0], 1.f); atomicAdd(&s_load[i1], 1.f);
    float y[10];
    #pragma unroll
    for (int nn = 0; nn < 10; nn++)
        y[nn] = g0 * s_b2[i0 * 10 + nn] + g1 * s_b2[i1 * 10 + nn];
    #pragma unroll
    for (int k = 0; k < 128; k++) {
        float a = g0 * h[k];
        float b = g1 * h[k];
        const float* w0p = &s_W2[(i0 * 128 + k) * 10];
        const float* w1p = &s_W2[(i1 * 128 + k) * 10];
        #pragma unroll
        for (int nn = 0; nn < 10; nn++)
            y[nn] = fmaf(a, w0p[nn], fmaf(b, w1p[nn], y[nn]));
    }
    float m = y[0];
    #pragma unroll
    for (int nn = 1; nn < 10; nn++) m = fmaxf(m, y[nn]);
    float s = 0.f;
    #pragma unroll
    for (int nn = 0; nn < 10; nn++) s += expf(y[nn] - m);
    float ls = m + logf(s);
    float* op = logp + (size_t)row * 10;
    #pragma unroll
    for (int nn = 0; nn < 10; nn++) op[nn] = y[nn] - ls;
    __syncthreads();
    if (tid < 8) { atomicAdd(&imp2[tid], s_imp[tid]); atomicAdd(&load2[tid], s_load[tid]); }
}

// ---------------- loss ------------------------------------------------------
__device__ float cv_sq(const float* v)
{
    float m = 0.f;
    for (int i = 0; i < 8; i++) m += v[i];
    m *= 0.125f;
    float s = 0.f;
    for (int i = 0; i < 8; i++) { float d = v[i] - m; s += d * d; }
    float var = s * (1.f / 7.f);          // ddof=1
    return var / (m * m + 1e-10f);
}

__global__ void loss_kernel(const float* __restrict__ imp1, const float* __restrict__ load1,
                            const float* __restrict__ imp2, const float* __restrict__ load2,
                            float* __restrict__ out)
{
    if (threadIdx.x == 0) {
        float l = (cv_sq(imp1) + cv_sq(load1) + cv_sq(imp2) + cv_sq(load2)) * 3e-5f;
        out[0] = l;
    }
}

// ---------------------------------------------------------------------------
extern "C" void kernel_launch(void* const* d_in, const int* in_sizes, int n_in,
                              void* d_out, int out_size, void* d_ws, size_t ws_size,
                              hipStream_t stream)
{
    const float* x       = (const float*)d_in[0];
    const float* conv1_w = (const float*)d_in[1];
    const float* conv1_b = (const float*)d_in[2];
    const float* conv2_w = (const float*)d_in[3];
    const float* conv2_b = (const float*)d_in[4];
    const float* w_gate1 = (const float*)d_in[5];
    const float* W1      = (const float*)d_in[6];
    const float* b1      = (const float*)d_in[7];
    const float* w_gate2 = (const float*)d_in[8];
    const float* W2      = (const float*)d_in[9];
    const float* b2      = (const float*)d_in[10];

    char* ws = (char*)d_ws;
    float* h_flat    = (float*)(ws + OFF_HFLAT);
    float* h2quad    = (float*)(ws + OFF_H2Q);
    int*   rows_list = (int*)  (ws + OFF_ROWS);
    float* gate_list = (float*)(ws + OFF_GATES);
    int*   cnt1      = (int*)  (ws + OFF_SMALL);
    float* imp1      = (float*)(ws + OFF_SMALL) + 8;
    float* load1     = (float*)(ws + OFF_SMALL) + 16;
    float* imp2      = (float*)(ws + OFF_SMALL) + 24;
    float* load2     = (float*)(ws + OFF_SMALL) + 32;

    float* logp_out = (float*)d_out;            // [4096,10]
    float* gt1_out  = (float*)d_out + 40960;    // [4096,8]
    float* gt2_out  = (float*)d_out + 73728;    // [4096,8]
    float* loss_out = (float*)d_out + 106496;   // [1]

    hipMemsetAsync(ws + OFF_SMALL, 0, 40 * sizeof(float), stream);

    conv_fused<<<4096, 512, 0, stream>>>(x, conv1_w, conv1_b, conv2_w, conv2_b, h_flat);
    gate1_kernel<<<1024, 256, 0, stream>>>(h_flat, w_gate1, gt1_out,
                                           rows_list, gate_list, cnt1, imp1, load1);
    moe1_gemm<<<dim3(8, 128), 512, 0, stream>>>(h_flat, W1, b1, rows_list, gate_list,
                                                cnt1, h2quad);
    moe2_head<<<64, 64, 0, stream>>>(h2quad, w_gate2, W2, b2,
                                     gt2_out, logp_out, imp2, load2);
    loss_kernel<<<1, 64, 0, stream>>>(imp1, load1, imp2, load2, loss_out);
}

// Round 16
// 2761.587 us; speedup vs baseline: 1.3666x; 1.0500x over previous
//
#include <hip/hip_runtime.h>
#include <cstdint>
#include <cstddef>

// ---------------------------------------------------------------------------
//   x:[4096,1,30,30] -> conv1(32,3x3)+relu -> conv2(64,3x3)+relu -> maxpool2
//   -> flatten [4096,10816] -> MoE(top2, 8 experts, 10816->128) -> relu
//   -> MoE(top2, 8 experts, 128->10) -> log_softmax
//   outputs: logp[4096,10], gt_l1[4096,8], gt_l2[4096,8], loss[1]
// ---------------------------------------------------------------------------

// ws layout (bytes)
static const size_t OFF_HFLAT = 0;                                        // 177,209,344
static const size_t OFF_H2Q   = (size_t)4096 * 10816 * 4;                 // 4096*4*128*4 = 8,388,608
static const size_t OFF_ROWS  = OFF_H2Q + (size_t)4096 * 4 * 128 * 4;     // 8*4096*4
static const size_t OFF_GATES = OFF_ROWS + (size_t)8 * 4096 * 4;          // 8*4096*4
static const size_t OFF_SMALL = OFF_GATES + (size_t)8 * 4096 * 4;         // 40*4
// small: [0..7] cnt(int) | [8..15] imp1 | [16..23] load1 | [24..31] imp2 | [32..39] load2

// ---------------- fused conv1 -> conv2 -> maxpool -> GATE1 ------------------
// ROUND 16: conv core = round 7 verbatim (best verified: ~1900 us, WRITE
// exactly 173 MB, FETCH 8 MB, VGPR 128, zero spill). NEW: gate layer 1 fused
// into the epilogue -- the full hflat row (10816 f) is already in s_out (LDS),
// so logits = row . w_gate1 are computed in-block (512 thr x 21 strided LDS
// reads x 8 FMA -> wave shfl-reduce -> 8x8 LDS reduce -> thread-0 top-2 +
// scatter). Eliminates gate1's 177 MB hflat re-read + one dispatch.
// Session-closed findings: (512,2) -> 128 VGPR spill-free; (*,4) or >512-thr
// blocks -> 64 VGPR + multi-GB spill traffic; 1 block/CU at VGPR>=120 for
// any LDS in [64K,92K] -- occupancy is a fixed constraint for this kernel.

template<int PC>
__device__ __forceinline__ void ld_row(float* r, const float* __restrict__ p)
{
    #pragma unroll
    for (int c = 0; c < PC; c += 2) {
        float2 t = *(const float2*)(p + c);
        r[c] = t.x; r[c + 1] = t.y;
    }
}

template<int TC>
__device__ __forceinline__ void fma_ky(float acc[4][2][8], const float* ra, const float* rb,
                                       const float* __restrict__ wk)
{
    #pragma unroll
    for (int kx = 0; kx < 3; ++kx) {
        float4 w = *(const float4*)(wk + kx * 68);   // [kk][oc pad68]
        #pragma unroll
        for (int c = 0; c < 2 * TC; ++c) {
            float ia = ra[c + kx], ib = rb[c + kx];
            acc[0][0][c] = fmaf(ia, w.x, acc[0][0][c]);
            acc[1][0][c] = fmaf(ia, w.y, acc[1][0][c]);
            acc[2][0][c] = fmaf(ia, w.z, acc[2][0][c]);
            acc[3][0][c] = fmaf(ia, w.w, acc[3][0][c]);
            acc[0][1][c] = fmaf(ib, w.x, acc[0][1][c]);
            acc[1][1][c] = fmaf(ib, w.y, acc[1][1][c]);
            acc[2][1][c] = fmaf(ib, w.z, acc[2][1][c]);
            acc[3][1][c] = fmaf(ib, w.w, acc[3][1][c]);
        }
    }
}

template<int TC>
__device__ __forceinline__ void conv2_accum(const float* __restrict__ hb,
                                            const float* __restrict__ wb,
                                            float acc[4][2][8])
{
    #pragma unroll 2
    for (int icl = 0; icl < 8; ++icl) {
        const float* h = hb + icl * 504;   // [icl][r][28] band
        const float* w = wb + icl * 612;   // [icl][kk 0..8][68]
        float r0[2 * TC + 2], r1[2 * TC + 2], r2[2 * TC + 2], r3[2 * TC + 2];
        ld_row<2 * TC + 2>(r0, h);
        ld_row<2 * TC + 2>(r1, h + 28);
        fma_ky<TC>(acc, r0, r1, w);
        ld_row<2 * TC + 2>(r2, h + 56);
        fma_ky<TC>(acc, r1, r2, w + 204);
        ld_row<2 * TC + 2>(r3, h + 84);
        fma_ky<TC>(acc, r2, r3, w + 408);
    }
}

__global__ __launch_bounds__(512, 2)
void conv_fused(const float* __restrict__ x,
                const float* __restrict__ w1, const float* __restrict__ b1,
                const float* __restrict__ w2, const float* __restrict__ b2,
                const float* __restrict__ wg1,
                float* __restrict__ hflat, float* __restrict__ gt1,
                int* __restrict__ rows_list, float* __restrict__ gate_list,
                int* __restrict__ cnt, float* __restrict__ imp, float* __restrict__ load)
{
    __shared__ float s_in[900];
    __shared__ float s_w1[288];
    __shared__ float s_b1[32];
    __shared__ float s_b2[64];
    __shared__ float s_h1[4032];     // [icl(8)][r(18)][c(28)] band
    __shared__ float s_w2c[4896];    // [kk(72)=icl*9+k][oc(64) pad68] current ic-chunk
    __shared__ float s_out[10816];   // full pooled image [64 oc][13][13]
    __shared__ float s_red[64];      // [wave(8)][e(8)] gate partial sums

    const int img = blockIdx.x, tid = threadIdx.x;

    const float* xin = x + (size_t)img * 900;
    for (int i = tid; i < 900; i += 512) s_in[i] = xin[i];
    if (tid < 288) s_w1[tid] = w1[tid];
    if (tid < 32) s_b1[tid] = b1[tid];
    if (tid < 64) s_b2[tid] = b2[tid];
    __syncthreads();   // RACE FIX: acc init below reads s_b2

    const int ct  = tid >> 7;          // 0..3 (wave-uniform: 2 waves per ct)
    const int prl = (tid >> 4) & 7;    // 0..7
    const int ocg = tid & 15;          // 0..15 -> oc ocg*4..+3
    const int c0  = ct * 6;            // pre-col start: 0,6,12,18
    const int pc0 = ct * 3;            // pooled-col start
    const int TCp = (ct < 3) ? 3 : 4;  // pooled cols this thread

    const float* hb = s_h1 + 2 * prl * 28 + c0;
    const float* wb = s_w2c + ocg * 4;

    #pragma unroll 1
    for (int band = 0; band < 2; ++band) {
        const int rb = band * 5;                 // pooled rows rb..rb+7
        float acc[4][2][8];
        #pragma unroll
        for (int o = 0; o < 4; ++o) {
            float bb = s_b2[ocg * 4 + o];
            #pragma unroll
            for (int r = 0; r < 2; ++r)
                #pragma unroll
                for (int c = 0; c < 8; ++c) acc[o][r][c] = bb;
        }
        #pragma unroll 1
        for (int ch = 0; ch < 4; ++ch) {
            __syncthreads();   // previous compute done before restaging s_h1/s_w2c
            // --- stage conv1: pre rows 2rb..2rb+17, ic chunk ch*8..+7 ---
            #pragma unroll
            for (int it = 0; it < 8; ++it) {
                int i2 = it * 512 + tid;
                if (i2 < 4032) {
                    int q = i2 / 28;           // icl*18 + r
                    int c = i2 - q * 28;
                    int icl = q / 18;
                    int r = q - icl * 18;
                    int ic = ch * 8 + icl;
                    int grow = 2 * rb + r;     // <= 27
                    const float* wp = &s_w1[ic * 9];
                    const float* ip = &s_in[grow * 30 + c];
                    float v = s_b1[ic];
                    v = fmaf(ip[0],  wp[0], v); v = fmaf(ip[1],  wp[1], v); v = fmaf(ip[2],  wp[2], v);
                    v = fmaf(ip[30], wp[3], v); v = fmaf(ip[31], wp[4], v); v = fmaf(ip[32], wp[5], v);
                    v = fmaf(ip[60], wp[6], v); v = fmaf(ip[61], wp[7], v); v = fmaf(ip[62], wp[8], v);
                    s_h1[i2] = fmaxf(v, 0.f);
                }
            }
            // --- stage conv2 weights: [72][oc(64) pad68] for this ic chunk ---
            #pragma unroll
            for (int it = 0; it < 9; ++it) {
                int i = it * 512 + tid;        // 0..4607 exact (9*512 = 4608 = 64*72)
                int oc = i / 72;
                int r = i - oc * 72;
                s_w2c[r * 68 + oc] = w2[oc * 288 + ch * 72 + r];
            }
            __syncthreads();
            if (ct < 3) conv2_accum<3>(hb, wb, acc);
            else        conv2_accum<4>(hb, wb, acc);
        }
        // --- pool 2x2 + relu -> s_out (separate array; no sync needed:
        //     next band's ch=0 __syncthreads covers the s_h1 reuse) ---
        #pragma unroll
        for (int o = 0; o < 4; ++o)
            #pragma unroll
            for (int c = 0; c < 4; ++c) {
                if (c < TCp) {
                    float m = fmaxf(fmaxf(acc[o][0][2 * c], acc[o][0][2 * c + 1]),
                                    fmaxf(acc[o][1][2 * c], acc[o][1][2 * c + 1]));
                    s_out[(ocg * 4 + o) * 169 + (rb + prl) * 13 + pc0 + c] = fmaxf(m, 0.f);
                }
            }
    }
    __syncthreads();   // s_out complete
    // --- single dense aligned copy-out: 10816 floats, base 128-aligned ---
    float* gbase = hflat + (size_t)img * 10816;
    #pragma unroll
    for (int it = 0; it < 22; ++it) {
        int i = it * 512 + tid;
        if (i < 10816) gbase[i] = s_out[i];
    }
    // --- fused gate1: logits = s_out . wg1 (10816 x 8), top-2, scatter ------
    float part[8] = {0.f, 0.f, 0.f, 0.f, 0.f, 0.f, 0.f, 0.f};
    for (int i = tid; i < 10816; i += 512) {
        float v = s_out[i];                       // conflict-free: lane-consecutive
        const float4* wq = (const float4*)(wg1 + (size_t)i * 8);
        float4 wa = wq[0], wbv = wq[1];           // L2-hot (346 KB total)
        part[0] = fmaf(v, wa.x,  part[0]); part[1] = fmaf(v, wa.y,  part[1]);
        part[2] = fmaf(v, wa.z,  part[2]); part[3] = fmaf(v, wa.w,  part[3]);
        part[4] = fmaf(v, wbv.x, part[4]); part[5] = fmaf(v, wbv.y, part[5]);
        part[6] = fmaf(v, wbv.z, part[6]); part[7] = fmaf(v, wbv.w, part[7]);
    }
    #pragma unroll
    for (int e = 0; e < 8; e++)
        #pragma unroll
        for (int off = 32; off > 0; off >>= 1)
            part[e] += __shfl_down(part[e], off, 64);
    const int wv = tid >> 6;
    if ((tid & 63) == 0)
        #pragma unroll
        for (int e = 0; e < 8; e++) s_red[wv * 8 + e] = part[e];
    __syncthreads();
    if (tid == 0) {
        float lg[8];
        #pragma unroll
        for (int e = 0; e < 8; e++) {
            float s = 0.f;
            #pragma unroll
            for (int w = 0; w < 8; w++) s += s_red[w * 8 + e];
            lg[e] = s;
        }
        int i0 = 0; float v0 = lg[0];
        #pragma unroll
        for (int e = 1; e < 8; e++) if (lg[e] > v0) { v0 = lg[e]; i0 = e; }
        int i1 = -1; float v1 = -1e30f;
        #pragma unroll
        for (int e = 0; e < 8; e++) if (e != i0 && lg[e] > v1) { v1 = lg[e]; i1 = e; }
        float ex = expf(v1 - v0);
        float g0 = 1.f / (1.f + ex);
        float g1 = ex / (1.f + ex);
        float* gp = gt1 + (size_t)img * 8;
        #pragma unroll
        for (int e = 0; e < 8; e++) gp[e] = 0.f;
        gp[i0] = g0; gp[i1] = g1;
        atomicAdd(&imp[i0], g0); atomicAdd(&imp[i1], g1);
        atomicAdd(&load[i0], 1.f); atomicAdd(&load[i1], 1.f);
        int p0 = atomicAdd(&cnt[i0], 1);
        rows_list[i0 * 4096 + p0] = img * 2 + 0; gate_list[i0 * 4096 + p0] = g0;
        int p1 = atomicAdd(&cnt[i1], 1);
        rows_list[i1 * 4096 + p1] = img * 2 + 1; gate_list[i1 * 4096 + p1] = g1;
    }
}

// ---------------- MoE1 expert GEMM: M=64, N=128, K-split x2, 512 thr --------
// 512 threads (8 waves): 2 waves/SIMD at ~1 block/CU (round 15: -90 us total).
__global__ __launch_bounds__(512)
void moe1_gemm(const float* __restrict__ hflat, const float* __restrict__ W1,
               const float* __restrict__ b1g,
               const int* __restrict__ rows_list, const float* __restrict__ gate_list,
               const int* __restrict__ cnt, float* __restrict__ h2quad)
{
    const int e  = blockIdx.x;
    const int t  = blockIdx.y >> 1;
    const int kh = blockIdx.y & 1;
    const int n = cnt[e];
    if (t * 64 >= n) return;
    __shared__ float sA[32][68];     // [k][m] pad 68
    __shared__ float sB[32][132];    // [k][n] pad 132
    __shared__ int   s_rows[64];
    __shared__ float s_gate[64];
    const int tid = threadIdx.x;
    const int mr = (n - t * 64 < 64) ? (n - t * 64) : 64;
    if (tid < 64) {
        int idx = t * 64 + ((tid < mr) ? tid : 0);
        s_rows[tid] = rows_list[e * 4096 + idx];
        s_gate[tid] = (tid < mr) ? gate_list[e * 4096 + t * 64 + tid] : 0.f;
    }
    __syncthreads();
    float acc[4][4];
    #pragma unroll
    for (int i = 0; i < 4; i++)
        #pragma unroll
        for (int j = 0; j < 4; j++) acc[i][j] = 0.f;
    const int tm = tid >> 5;            // 0..15 -> rows tm*4..+3
    const int tn = tid & 31;            // cols tn*4..+3
    const float* Wb = W1 + (size_t)e * 10816 * 128;
    const int ar = tid >> 3;            // 0..63
    const int ak = (tid & 7) * 4;       // 0,4,...,28
    const int bk = tid >> 4;            // 0..31
    const int bn = (tid & 15) * 8;      // 0,8,...,120
    const int kbase = kh * 5408;
    const float* agp = hflat + (size_t)(s_rows[ar] >> 1) * 10816 + kbase;
    for (int k0 = 0; k0 < 5408; k0 += 32) {
        float4 a0 = *(const float4*)(agp + k0 + ak);
        const float4* bsrc = (const float4*)(Wb + (size_t)(kbase + k0 + bk) * 128 + bn);
        float4 b0 = bsrc[0], b1v = bsrc[1];
        __syncthreads();
        sA[ak + 0][ar] = a0.x; sA[ak + 1][ar] = a0.y;
        sA[ak + 2][ar] = a0.z; sA[ak + 3][ar] = a0.w;
        *(float4*)&sB[bk][bn + 0] = b0; *(float4*)&sB[bk][bn + 4] = b1v;
        __syncthreads();
        #pragma unroll
        for (int k = 0; k < 32; k++) {
            float4 av = *(const float4*)&sA[k][tm * 4];
            float4 bv = *(const float4*)&sB[k][tn * 4];
            acc[0][0] = fmaf(av.x, bv.x, acc[0][0]); acc[0][1] = fmaf(av.x, bv.y, acc[0][1]);
            acc[0][2] = fmaf(av.x, bv.z, acc[0][2]); acc[0][3] = fmaf(av.x, bv.w, acc[0][3]);
            acc[1][0] = fmaf(av.y, bv.x, acc[1][0]); acc[1][1] = fmaf(av.y, bv.y, acc[1][1]);
            acc[1][2] = fmaf(av.y, bv.z, acc[1][2]); acc[1][3] = fmaf(av.y, bv.w, acc[1][3]);
            acc[2][0] = fmaf(av.z, bv.x, acc[2][0]); acc[2][1] = fmaf(av.z, bv.y, acc[2][1]);
            acc[2][2] = fmaf(av.z, bv.z, acc[2][2]); acc[2][3] = fmaf(av.z, bv.w, acc[2][3]);
            acc[3][0] = fmaf(av.w, bv.x, acc[3][0]); acc[3][1] = fmaf(av.w, bv.y, acc[3][1]);
            acc[3][2] = fmaf(av.w, bv.z, acc[3][2]); acc[3][3] = fmaf(av.w, bv.w, acc[3][3]);
        }
    }
    const float* b1e = b1g + e * 128;
    float bx = (kh == 0) ? b1e[tn * 4 + 0] : 0.f;
    float by = (kh == 0) ? b1e[tn * 4 + 1] : 0.f;
    float bz = (kh == 0) ? b1e[tn * 4 + 2] : 0.f;
    float bw = (kh == 0) ? b1e[tn * 4 + 3] : 0.f;
    #pragma unroll
    for (int i = 0; i < 4; i++) {
        int m = tm * 4 + i;
        if (m < mr) {
            float g = s_gate[m];
            int rs = s_rows[m];
            float4 o;
            o.x = (acc[i][0] + bx) * g;
            o.y = (acc[i][1] + by) * g;
            o.z = (acc[i][2] + bz) * g;
            o.w = (acc[i][3] + bw) * g;
            *(float4*)(h2quad + ((size_t)rs * 2 + kh) * 128 + tn * 4) = o;
        }
    }
}

// ---------------- MoE2 head + log_softmax ----------------------------------
__global__ __launch_bounds__(64)
void moe2_head(const float* __restrict__ h2quad, const float* __restrict__ wg2,
               const float* __restrict__ W2, const float* __restrict__ b2,
               float* __restrict__ gt2, float* __restrict__ logp,
               float* __restrict__ imp2, float* __restrict__ load2)
{
    __shared__ float s_wg[128 * 8];
    __shared__ float s_W2[8 * 128 * 10];
    __shared__ float s_b2[80];
    __shared__ float s_imp[8], s_load[8];
    const int tid = threadIdx.x;
    for (int i = tid; i < 1024; i += 64) s_wg[i] = wg2[i];
    for (int i = tid; i < 10240; i += 64) s_W2[i] = W2[i];
    for (int i = tid; i < 80; i += 64) s_b2[i] = b2[i];
    if (tid < 8) { s_imp[tid] = 0.f; s_load[tid] = 0.f; }
    __syncthreads();
    const int row = blockIdx.x * 64 + tid;
    float h[128];
    const float* p0 = h2quad + (size_t)row * 512;
    #pragma unroll
    for (int i = 0; i < 128; i += 4) {
        float4 a = *(const float4*)(p0 + i);
        float4 b = *(const float4*)(p0 + 128 + i);
        float4 c = *(const float4*)(p0 + 256 + i);
        float4 d = *(const float4*)(p0 + 384 + i);
        h[i + 0] = fmaxf(a.x + b.x + c.x + d.x, 0.f);
        h[i + 1] = fmaxf(a.y + b.y + c.y + d.y, 0.f);
        h[i + 2] = fmaxf(a.z + b.z + c.z + d.z, 0.f);
        h[i + 3] = fmaxf(a.w + b.w + c.w + d.w, 0.f);
    }
    float lg[8] = {0.f, 0.f, 0.f, 0.f, 0.f, 0.f, 0.f, 0.f};
    #pragma unroll
    for (int k = 0; k < 128; k++) {
        float hv = h[k];
        #pragma unroll
        for (int e = 0; e < 8; e++) lg[e] = fmaf(hv, s_wg[k * 8 + e], lg[e]);
    }
    int i0 = 0; float v0 = lg[0];
    #pragma unroll
    for (int e = 1; e < 8; e++) if (lg[e] > v0) { v0 = lg[e]; i0 = e; }
    int i1 = -1; float v1 = -1e30f;
    #pragma unroll
    for (int e = 0; e < 8; e++) if (e != i0 && lg[e] > v1) { v1 = lg[e]; i1 = e; }
    float ex = expf(v1 - v0);
    float g0 = 1.f / (1.f + ex);
    float g1 = ex / (1.f + ex);
    float* gp = gt2 + (size_t)row * 8;
    #pragma unroll
    for (int e = 0; e < 8; e++) gp[e] = 0.f;
    gp[i0] = g0; gp[i1] = g1;
    atomicAdd(&s_imp[i0], g0); atomicAdd(&s_imp[i1], g1);
    atomicAdd(&s_load[i0], 1.f); atomicAdd(&s_load[i1], 1.f);
    float y[10];
    #pragma unroll
    for (int nn = 0; nn < 10; nn++)
        y[nn] = g0 * s_b2[i0 * 10 + nn] + g1 * s_b2[i1 * 10 + nn];
    #pragma unroll
    for (int k = 0; k < 128; k++) {
        float a = g0 * h[k];
        float b = g1 * h[k];
        const float* w0p = &s_W2[(i0 * 128 + k) * 10];
        const float* w1p = &s_W2[(i1 * 128 + k) * 10];
        #pragma unroll
        for (int nn = 0; nn < 10; nn++)
            y[nn] = fmaf(a, w0p[nn], fmaf(b, w1p[nn], y[nn]));
    }
    float m = y[0];
    #pragma unroll
    for (int nn = 1; nn < 10; nn++) m = fmaxf(m, y[nn]);
    float s = 0.f;
    #pragma unroll
    for (int nn = 0; nn < 10; nn++) s += expf(y[nn] - m);
    float ls = m + logf(s);
    float* op = logp + (size_t)row * 10;
    #pragma unroll
    for (int nn = 0; nn < 10; nn++) op[nn] = y[nn] - ls;
    __syncthreads();
    if (tid < 8) { atomicAdd(&imp2[tid], s_imp[tid]); atomicAdd(&load2[tid], s_load[tid]); }
}

// ---------------- loss ------------------------------------------------------
__device__ float cv_sq(const float* v)
{
    float m = 0.f;
    for (int i = 0; i < 8; i++) m += v[i];
    m *= 0.125f;
    float s = 0.f;
    for (int i = 0; i < 8; i++) { float d = v[i] - m; s += d * d; }
    float var = s * (1.f / 7.f);          // ddof=1
    return var / (m * m + 1e-10f);
}

__global__ void loss_kernel(const float* __restrict__ imp1, const float* __restrict__ load1,
                            const float* __restrict__ imp2, const float* __restrict__ load2,
                            float* __restrict__ out)
{
    if (threadIdx.x == 0) {
        float l = (cv_sq(imp1) + cv_sq(load1) + cv_sq(imp2) + cv_sq(load2)) * 3e-5f;
        out[0] = l;
    }
}

// ---------------------------------------------------------------------------
extern "C" void kernel_launch(void* const* d_in, const int* in_sizes, int n_in,
                              void* d_out, int out_size, void* d_ws, size_t ws_size,
                              hipStream_t stream)
{
    const float* x       = (const float*)d_in[0];
    const float* conv1_w = (const float*)d_in[1];
    const float* conv1_b = (const float*)d_in[2];
    const float* conv2_w = (const float*)d_in[3];
    const float* conv2_b = (const float*)d_in[4];
    const float* w_gate1 = (const float*)d_in[5];
    const float* W1      = (const float*)d_in[6];
    const float* b1      = (const float*)d_in[7];
    const float* w_gate2 = (const float*)d_in[8];
    const float* W2      = (const float*)d_in[9];
    const float* b2      = (const float*)d_in[10];

    char* ws = (char*)d_ws;
    float* h_flat    = (float*)(ws + OFF_HFLAT);
    float* h2quad    = (float*)(ws + OFF_H2Q);
    int*   rows_list = (int*)  (ws + OFF_ROWS);
    float* gate_list = (float*)(ws + OFF_GATES);
    int*   cnt1      = (int*)  (ws + OFF_SMALL);
    float* imp1      = (float*)(ws + OFF_SMALL) + 8;
    float* load1     = (float*)(ws + OFF_SMALL) + 16;
    float* imp2      = (float*)(ws + OFF_SMALL) + 24;
    float* load2     = (float*)(ws + OFF_SMALL) + 32;

    float* logp_out = (float*)d_out;            // [4096,10]
    float* gt1_out  = (float*)d_out + 40960;    // [4096,8]
    float* gt2_out  = (float*)d_out + 73728;    // [4096,8]
    float* loss_out = (float*)d_out + 106496;   // [1]

    hipMemsetAsync(ws + OFF_SMALL, 0, 40 * sizeof(float), stream);

    conv_fused<<<4096, 512, 0, stream>>>(x, conv1_w, conv1_b, conv2_w, conv2_b,
                                         w_gate1, h_flat, gt1_out,
                                         rows_list, gate_list, cnt1, imp1, load1);
    moe1_gemm<<<dim3(8, 128), 512, 0, stream>>>(h_flat, W1, b1, rows_list, gate_list,
                                                cnt1, h2quad);
    moe2_head<<<64, 64, 0, stream>>>(h2quad, w_gate2, W2, b2,
                                     gt2_out, logp_out, imp2, load2);
    loss_kernel<<<1, 64, 0, stream>>>(imp1, load1, imp2, load2, loss_out);
}